// Round 1
// baseline (4599.044 us; speedup 1.0000x reference)
//
#include <hip/hip_runtime.h>

// Problem constants (AttentionXL): CUR=1024, FULL=2048, BS=4, D=1024, HN=16, HD=64
#define PREV 1024

// ---------------------------------------------------------------------------
// Generic fp32 GEMM: C = A(MxK) @ B(KxN) + bias(N).  BM=BN=128, BK=8,
// 256 threads, 8x8 per-thread tile. M%128==0, N%128==0, K%8==0 by construction.
// ---------------------------------------------------------------------------
__global__ __launch_bounds__(256) void sgemm_bias(
    const float* __restrict__ A, const float* __restrict__ B,
    const float* __restrict__ bias, float* __restrict__ C,
    int M, int N, int K) {
  __shared__ float As[8][128];  // transposed A tile
  __shared__ float Bs[8][128];
  const int t = threadIdx.x;
  const int bm = blockIdx.y * 128;
  const int bn = blockIdx.x * 128;
  const int tx = t & 15, ty = t >> 4;
  const int ar = t >> 1, ac = (t & 1) * 4;   // A: 128 rows x 2 float4
  const int br = t >> 5, bc = (t & 31) * 4;  // B: 8 rows x 32 float4
  float acc[8][8] = {};
  const float* Ap = A + (size_t)(bm + ar) * K + ac;
  const float* Bp = B + (size_t)br * N + bn + bc;
  for (int k0 = 0; k0 < K; k0 += 8) {
    const float4 av = *(const float4*)(Ap + k0);
    const float4 bv = *(const float4*)(Bp + (size_t)k0 * N);
    __syncthreads();
    As[ac + 0][ar] = av.x;
    As[ac + 1][ar] = av.y;
    As[ac + 2][ar] = av.z;
    As[ac + 3][ar] = av.w;
    *(float4*)&Bs[br][bc] = bv;
    __syncthreads();
#pragma unroll
    for (int kk = 0; kk < 8; ++kk) {
      float a0[8], b0[8];
      *(float4*)&a0[0] = *(const float4*)&As[kk][ty * 8];
      *(float4*)&a0[4] = *(const float4*)&As[kk][ty * 8 + 4];
      *(float4*)&b0[0] = *(const float4*)&Bs[kk][tx * 8];
      *(float4*)&b0[4] = *(const float4*)&Bs[kk][tx * 8 + 4];
#pragma unroll
      for (int i = 0; i < 8; ++i)
#pragma unroll
        for (int j = 0; j < 8; ++j) acc[i][j] += a0[i] * b0[j];
    }
  }
#pragma unroll
  for (int i = 0; i < 8; ++i) {
    const int row = bm + ty * 8 + i;
#pragma unroll
    for (int j = 0; j < 8; j += 4) {
      const int col = bn + tx * 8 + j;
      float4 o;
      o.x = acc[i][j + 0] + bias[col + 0];
      o.y = acc[i][j + 1] + bias[col + 1];
      o.z = acc[i][j + 2] + bias[col + 2];
      o.w = acc[i][j + 3] + bias[col + 3];
      *(float4*)&C[(size_t)row * N + col] = o;
    }
  }
}

// ---------------------------------------------------------------------------
// out[row*16 + h] = sum_d uv[h*64+d] * mat[row*stride + h*64 + d]
// One block per row (stride=2048 for kv -> u.k ; stride=1024 for r -> v.r)
// ---------------------------------------------------------------------------
__global__ __launch_bounds__(256) void uv_dot(
    const float* __restrict__ mat, const float* __restrict__ uv,
    float* __restrict__ out, int stride) {
  const int row = blockIdx.x;
  const int t = threadIdx.x;
  const int h = t >> 4, dg = t & 15;  // d = dg*4..dg*4+3
  const float4 m4 = *(const float4*)(mat + (size_t)row * stride + h * 64 + dg * 4);
  const float4 u4 = *(const float4*)(uv + h * 64 + dg * 4);
  __shared__ float red[256];
  red[t] = m4.x * u4.x + m4.y * u4.y + m4.z * u4.z + m4.w * u4.w;
  __syncthreads();
  if (dg == 0) {
    float s = 0.f;
#pragma unroll
    for (int i = 0; i < 16; ++i) s += red[h * 16 + i];
    out[row * 16 + h] = s;
  }
}

// ---------------------------------------------------------------------------
// Fused attention, one block per (b, h, 32-query tile), 256 threads.
// scores[i][j] = (q_i.k_j + u.k_j + q_i.r_m + v.r_m) * 0.125, m = j-i+1023
// masked where j > i + PREV (== exactly the rel_shift garbage region).
// Online softmax over 32-wide key tiles; causal skip of all-masked tiles.
// ---------------------------------------------------------------------------
__global__ __launch_bounds__(256) void attn_kernel(
    const float* __restrict__ qws, const float* __restrict__ kvws,
    const float* __restrict__ rws, const float* __restrict__ ukws,
    const float* __restrict__ vrws, float* __restrict__ ows) {
  __shared__ float qs[32][68];
  __shared__ float ks[32][68];
  __shared__ float vs[32][68];
  __shared__ float rs[64][68];   // r rows m_base .. m_base+63
  __shared__ float Sc[32][36];   // content scores, then probabilities
  __shared__ float Ps[32][68];   // position scores q.r^T over the m window
  __shared__ float uks[32];
  __shared__ float vrs[64];
  __shared__ float row_m[32], row_l[32], row_a[32];

  const int t = threadIdx.x;
  const int i0 = blockIdx.x * 32;
  const int b = blockIdx.y >> 4;
  const int h = blockIdx.y & 15;
  const int tx = t & 15, ty = t >> 4;

#pragma unroll
  for (int rep = 0; rep < 2; ++rep) {
    const int idx = rep * 1024 + t * 4;
    const int ii = idx >> 6, d = idx & 63;
    *(float4*)&qs[ii][d] =
        *(const float4*)&qws[((size_t)((i0 + ii) * 4 + b) << 10) + h * 64 + d];
  }
  if (t < 32) { row_m[t] = -3.0e38f; row_l[t] = 0.0f; }

  float o00=0,o01=0,o02=0,o03=0,o10=0,o11=0,o12=0,o13=0;

  const int njt = blockIdx.x + 33;  // j-tiles with any unmasked entry
  for (int jt = 0; jt < njt; ++jt) {
    const int j0 = jt * 32;
    const int m_base = j0 - i0 + 992;  // m = j-i+1023, window of 63 values
    __syncthreads();  // previous tile's PV done before overwriting buffers
#pragma unroll
    for (int rep = 0; rep < 2; ++rep) {
      const int idx = rep * 1024 + t * 4;
      const int jj = idx >> 6, d = idx & 63;
      const size_t base = ((size_t)((j0 + jj) * 4 + b) << 11) + h * 64 + d;
      *(float4*)&ks[jj][d] = *(const float4*)&kvws[base];
      *(float4*)&vs[jj][d] = *(const float4*)&kvws[base + 1024];
    }
#pragma unroll
    for (int rep = 0; rep < 4; ++rep) {
      const int idx = rep * 1024 + t * 4;
      const int mm = idx >> 6, d = idx & 63;
      int m = m_base + mm; if (m > 2047) m = 2047;  // clamped rows feed only masked entries
      *(float4*)&rs[mm][d] = *(const float4*)&rws[((size_t)m << 10) + h * 64 + d];
    }
    if (t < 32) uks[t] = ukws[((j0 + t) * 4 + b) * 16 + h];
    if (t >= 64 && t < 128) {
      const int mm = t - 64;
      int m = m_base + mm; if (m > 2047) m = 2047;
      vrs[mm] = vrws[m * 16 + h];
    }
    __syncthreads();
    // content scores: 2x2 per thread
    {
      const int r0 = ty * 2, c0 = tx * 2;
      float c00=0,c01=0,c10=0,c11=0;
#pragma unroll
      for (int d = 0; d < 64; d += 4) {
        const float4 a0 = *(const float4*)&qs[r0][d];
        const float4 a1 = *(const float4*)&qs[r0 + 1][d];
        const float4 b0 = *(const float4*)&ks[c0][d];
        const float4 b1 = *(const float4*)&ks[c0 + 1][d];
        c00 += a0.x*b0.x + a0.y*b0.y + a0.z*b0.z + a0.w*b0.w;
        c01 += a0.x*b1.x + a0.y*b1.y + a0.z*b1.z + a0.w*b1.w;
        c10 += a1.x*b0.x + a1.y*b0.y + a1.z*b0.z + a1.w*b0.w;
        c11 += a1.x*b1.x + a1.y*b1.y + a1.z*b1.z + a1.w*b1.w;
      }
      Sc[r0][c0] = c00; Sc[r0][c0 + 1] = c01;
      Sc[r0 + 1][c0] = c10; Sc[r0 + 1][c0 + 1] = c11;
    }
    // position scores: P = q . rs^T, 2x4 per thread over 64 m-columns
    {
      const int r0 = ty * 2, c0 = tx * 4;
      float p00=0,p01=0,p02=0,p03=0,p10=0,p11=0,p12=0,p13=0;
#pragma unroll
      for (int d = 0; d < 64; d += 4) {
        const float4 a0 = *(const float4*)&qs[r0][d];
        const float4 a1 = *(const float4*)&qs[r0 + 1][d];
        const float4 g0 = *(const float4*)&rs[c0][d];
        const float4 g1 = *(const float4*)&rs[c0 + 1][d];
        const float4 g2 = *(const float4*)&rs[c0 + 2][d];
        const float4 g3 = *(const float4*)&rs[c0 + 3][d];
        p00 += a0.x*g0.x + a0.y*g0.y + a0.z*g0.z + a0.w*g0.w;
        p01 += a0.x*g1.x + a0.y*g1.y + a0.z*g1.z + a0.w*g1.w;
        p02 += a0.x*g2.x + a0.y*g2.y + a0.z*g2.z + a0.w*g2.w;
        p03 += a0.x*g3.x + a0.y*g3.y + a0.z*g3.z + a0.w*g3.w;
        p10 += a1.x*g0.x + a1.y*g0.y + a1.z*g0.z + a1.w*g0.w;
        p11 += a1.x*g1.x + a1.y*g1.y + a1.z*g1.z + a1.w*g1.w;
        p12 += a1.x*g2.x + a1.y*g2.y + a1.z*g2.z + a1.w*g2.w;
        p13 += a1.x*g3.x + a1.y*g3.y + a1.z*g3.z + a1.w*g3.w;
      }
      *(float4*)&Ps[r0][c0]     = make_float4(p00, p01, p02, p03);
      *(float4*)&Ps[r0 + 1][c0] = make_float4(p10, p11, p12, p13);
    }
    __syncthreads();
    // online softmax, one thread per query row
    if (t < 32) {
      const int ii = t;
      float srow[32];
      float mx = -3.0e38f;
#pragma unroll
      for (int jj = 0; jj < 32; ++jj) {
        const int ml = jj - ii + 31;  // local r/P index, in [0,62]
        float sv = (Sc[ii][jj] + uks[jj] + Ps[ii][ml] + vrs[ml]) * 0.125f;
        if (j0 + jj > i0 + ii + PREV) sv = -3.0e38f;
        srow[jj] = sv;
        mx = fmaxf(mx, sv);
      }
      const float m_old = row_m[ii];
      const float m_new = fmaxf(m_old, mx);
      const float a = __expf(m_old - m_new);
      float l = row_l[ii] * a;
#pragma unroll
      for (int jj = 0; jj < 32; ++jj) {
        const float e = __expf(srow[jj] - m_new);
        Sc[ii][jj] = e;  // overwrite with probability weight
        l += e;
      }
      row_m[ii] = m_new; row_l[ii] = l; row_a[ii] = a;
    }
    __syncthreads();
    // PV accumulate: rows ty*2..+1, cols tx*4..+3
    {
      const int r0 = ty * 2, c0 = tx * 4;
      const float a0 = row_a[r0], a1 = row_a[r0 + 1];
      o00*=a0; o01*=a0; o02*=a0; o03*=a0;
      o10*=a1; o11*=a1; o12*=a1; o13*=a1;
#pragma unroll
      for (int jj = 0; jj < 32; ++jj) {
        const float p0 = Sc[r0][jj];
        const float p1 = Sc[r0 + 1][jj];
        const float4 vv = *(const float4*)&vs[jj][c0];
        o00 += p0*vv.x; o01 += p0*vv.y; o02 += p0*vv.z; o03 += p0*vv.w;
        o10 += p1*vv.x; o11 += p1*vv.y; o12 += p1*vv.z; o13 += p1*vv.w;
      }
    }
  }
  const int r0 = ty * 2, c0 = tx * 4;
  const float n0 = 1.0f / row_l[r0];
  const float n1 = 1.0f / row_l[r0 + 1];
  *(float4*)&ows[((size_t)((i0 + r0) * 4 + b) << 10) + h * 64 + c0] =
      make_float4(o00 * n0, o01 * n0, o02 * n0, o03 * n0);
  *(float4*)&ows[((size_t)((i0 + r0 + 1) * 4 + b) << 10) + h * 64 + c0] =
      make_float4(o10 * n1, o11 * n1, o12 * n1, o13 * n1);
}

// ---------------------------------------------------------------------------
extern "C" void kernel_launch(void* const* d_in, const int* in_sizes, int n_in,
                              void* d_out, int out_size, void* d_ws, size_t ws_size,
                              hipStream_t stream) {
  const float* inputs   = (const float*)d_in[0];   // (1024,4,1024)
  const float* pos_emb  = (const float*)d_in[1];   // (2048,1,1024)
  const float* full_inp = (const float*)d_in[2];   // (2048,4,1024)
  const float* u        = (const float*)d_in[3];   // (16,64)
  const float* v        = (const float*)d_in[4];   // (16,64)
  // d_in[5] = mask: recomputed analytically, unused
  const float* W_kv   = (const float*)d_in[6];
  const float* b_kv   = (const float*)d_in[7];
  const float* W_q    = (const float*)d_in[8];
  const float* b_q    = (const float*)d_in[9];
  const float* W_pos  = (const float*)d_in[10];
  const float* b_pos  = (const float*)d_in[11];
  const float* W_proj = (const float*)d_in[12];
  const float* b_proj = (const float*)d_in[13];
  float* out = (float*)d_out;

  float* ws      = (float*)d_ws;
  float* q_ws    = ws;                       // 4M floats  (4096x1024)
  float* kv_ws   = ws + (4u << 20);          // 16M floats (8192x2048)
  float* r_ws    = ws + (20u << 20);         // 2M floats  (2048x1024)
  float* attn_ws = ws + (22u << 20);         // 4M floats  (4096x1024)
  float* uk_ws   = ws + (26u << 20);         // 131072 floats (j,b,h)
  float* vr_ws   = uk_ws + 131072;           // 32768 floats  (m,h)

  const dim3 blk(256);
  sgemm_bias<<<dim3(8, 32),  blk, 0, stream>>>(inputs,   W_q,   b_q,   q_ws, 4096, 1024, 1024);
  sgemm_bias<<<dim3(16, 64), blk, 0, stream>>>(full_inp, W_kv,  b_kv,  kv_ws, 8192, 2048, 1024);
  sgemm_bias<<<dim3(8, 16),  blk, 0, stream>>>(pos_emb,  W_pos, b_pos, r_ws, 2048, 1024, 1024);
  uv_dot<<<dim3(8192), blk, 0, stream>>>(kv_ws, u, uk_ws, 2048);
  uv_dot<<<dim3(2048), blk, 0, stream>>>(r_ws,  v, vr_ws, 1024);
  attn_kernel<<<dim3(32, 64), blk, 0, stream>>>(q_ws, kv_ws, r_ws, uk_ws, vr_ws, attn_ws);
  sgemm_bias<<<dim3(8, 32),  blk, 0, stream>>>(attn_ws, W_proj, b_proj, out, 4096, 1024, 1024);
}

// Round 2
// 576.985 us; speedup vs baseline: 7.9708x; 7.9708x over previous
//
#include <hip/hip_runtime.h>

// AttentionXL: CUR=1024, FULL=2048, BS=4, D=1024, HN=16, HD=64, PREV=1024
// All heavy math in f16 MFMA (16x16x32), fp32 accumulate/softmax.

typedef _Float16 half8 __attribute__((ext_vector_type(8)));
typedef _Float16 half4v __attribute__((ext_vector_type(4)));
typedef float f32x4 __attribute__((ext_vector_type(4)));

typedef const __attribute__((address_space(1))) void* gas_ptr;
typedef __attribute__((address_space(3))) void* las_ptr;

__device__ __forceinline__ void load_lds16(const void* g, void* l) {
  __builtin_amdgcn_global_load_lds((gas_ptr)g, (las_ptr)l, 16, 0, 0);
}

// ---------------------------------------------------------------------------
// elementwise fp32 -> f16 (n4 = count of float4 groups)
// ---------------------------------------------------------------------------
__global__ __launch_bounds__(256) void f32_to_f16(
    const float* __restrict__ in, _Float16* __restrict__ out, int n4) {
  int idx = blockIdx.x * 256 + threadIdx.x;
  if (idx < n4) {
    float4 v = *(const float4*)(in + (size_t)idx * 4);
    half4v h;
    h[0] = (_Float16)v.x; h[1] = (_Float16)v.y;
    h[2] = (_Float16)v.z; h[3] = (_Float16)v.w;
    *(half4v*)(out + (size_t)idx * 4) = h;
  }
}

// ---------------------------------------------------------------------------
// weight convert+transpose: W f32 [K][N] -> Wt f16 [N][K].  64x64 tiles.
// ---------------------------------------------------------------------------
__global__ __launch_bounds__(256) void wt_f16(
    const float* __restrict__ W, _Float16* __restrict__ Wt, int K, int N) {
  __shared__ _Float16 tile[64][65];
  const int t = threadIdx.x;
  const int n0 = blockIdx.x * 64, k0 = blockIdx.y * 64;
  const int rr = t >> 2, cc = (t & 3) * 16;
#pragma unroll
  for (int i = 0; i < 4; ++i) {
    float4 v = *(const float4*)&W[(size_t)(k0 + rr) * N + n0 + cc + i * 4];
    tile[rr][cc + i * 4 + 0] = (_Float16)v.x;
    tile[rr][cc + i * 4 + 1] = (_Float16)v.y;
    tile[rr][cc + i * 4 + 2] = (_Float16)v.z;
    tile[rr][cc + i * 4 + 3] = (_Float16)v.w;
  }
  __syncthreads();
  const int n = t >> 2, kc = (t & 3) * 16;
#pragma unroll
  for (int i = 0; i < 4; ++i) {
    half4v h;
    h[0] = tile[kc + i * 4 + 0][n];
    h[1] = tile[kc + i * 4 + 1][n];
    h[2] = tile[kc + i * 4 + 2][n];
    h[3] = tile[kc + i * 4 + 3][n];
    *(half4v*)&Wt[(size_t)(n0 + n) * K + k0 + kc + i * 4] = h;
  }
}

// ---------------------------------------------------------------------------
// f16 MFMA GEMM: C[M][N] = A[M][K] @ Bt[N][K]^T + bias.  128x128x32 tiles,
// 256 threads = 2x2 waves, each wave 4x4 MFMA tiles of 16x16x32.
// MODE 0: f32 row-major out0[M][N]
// MODE 1: q   -> f16 out0 = qf[b*16+h][i][d]          (row=i*4+b, col=h*64+d)
// MODE 2: kv  -> f16 out0 = kf[bh][j][d], out1 = vfT[bh][d][j]
// MODE 3: r   -> f16 out0 = rf[h][m][d]               (row=m)
// ---------------------------------------------------------------------------
template <int MODE>
__global__ __launch_bounds__(256, 2) void gemm_f16(
    const _Float16* __restrict__ A, const _Float16* __restrict__ Bt,
    const float* __restrict__ bias, void* __restrict__ out0,
    void* __restrict__ out1, int M, int N, int K) {
  __shared__ _Float16 As[128 * 32];
  __shared__ _Float16 Bs[128 * 32];
  const int t = threadIdx.x, w = t >> 6, l = t & 63;
  const int l15 = l & 15, l4 = l >> 4;
  const int bm = blockIdx.y * 128, bn = blockIdx.x * 128;
  const int wm = (w >> 1) * 64, wn = (w & 1) * 64;

  f32x4 acc[4][4];
  const f32x4 z4 = {0.f, 0.f, 0.f, 0.f};
#pragma unroll
  for (int i = 0; i < 4; ++i)
#pragma unroll
    for (int j = 0; j < 4; ++j) acc[i][j] = z4;

  const char* Abase = (const char*)A + (size_t)bm * K * 2;
  const char* Bbase = (const char*)Bt + (size_t)bn * K * 2;
  char* Asl = (char*)As;
  char* Bsl = (char*)Bs;

  for (int k0 = 0; k0 < K; k0 += 32) {
    __syncthreads();
#pragma unroll
    for (int iss = 0; iss < 2; ++iss) {
      const int off = w * 1024 + iss * 4096 + l * 16;
      const int row = off >> 6, kb = off & 63;
      load_lds16(Abase + (size_t)row * (K * 2) + k0 * 2 + kb,
                 Asl + w * 1024 + iss * 4096);
      load_lds16(Bbase + (size_t)row * (K * 2) + k0 * 2 + kb,
                 Bsl + w * 1024 + iss * 4096);
    }
    __syncthreads();
    half8 af[4], bf[4];
#pragma unroll
    for (int mt = 0; mt < 4; ++mt)
      af[mt] = *(const half8*)&As[(wm + mt * 16 + l15) * 32 + l4 * 8];
#pragma unroll
    for (int nt = 0; nt < 4; ++nt)
      bf[nt] = *(const half8*)&Bs[(wn + nt * 16 + l15) * 32 + l4 * 8];
#pragma unroll
    for (int mt = 0; mt < 4; ++mt)
#pragma unroll
      for (int nt = 0; nt < 4; ++nt)
        acc[mt][nt] = __builtin_amdgcn_mfma_f32_16x16x32_f16(
            af[mt], bf[nt], acc[mt][nt], 0, 0, 0);
  }

#pragma unroll
  for (int mt = 0; mt < 4; ++mt)
#pragma unroll
    for (int r = 0; r < 4; ++r) {
      const int row = bm + wm + mt * 16 + l4 * 4 + r;
#pragma unroll
      for (int nt = 0; nt < 4; ++nt) {
        const int col = bn + wn + nt * 16 + l15;
        const float val = acc[mt][nt][r] + bias[col];
        if (MODE == 0) {
          ((float*)out0)[(size_t)row * N + col] = val;
        } else if (MODE == 1) {
          const int i = row >> 2, b = row & 3, h = col >> 6, d = col & 63;
          ((_Float16*)out0)[(((size_t)(b * 16 + h) * 1024 + i) << 6) + d] =
              (_Float16)val;
        } else if (MODE == 2) {
          const int j = row >> 2, b = row & 3;
          const int c = col & 1023, h = c >> 6, d = c & 63;
          if ((col >> 10) == 0)
            ((_Float16*)out0)[(((size_t)(b * 16 + h) * 2048 + j) << 6) + d] =
                (_Float16)val;
          else
            ((_Float16*)out1)[(((size_t)(b * 16 + h) * 64 + d) << 11) + j] =
                (_Float16)val;
        } else {
          const int h = col >> 6, d = col & 63;
          ((_Float16*)out0)[(((size_t)h * 2048 + row) << 6) + d] = (_Float16)val;
        }
      }
    }
}

// ---------------------------------------------------------------------------
// uk[bh][j] = sum_d u[h][d] * kf[bh][j][d]     (16 lanes per j)
// ---------------------------------------------------------------------------
__global__ __launch_bounds__(256) void uk_dot(
    const _Float16* __restrict__ kf, const float* __restrict__ u,
    float* __restrict__ uk) {
  const int t = threadIdx.x, bh = blockIdx.y, h = bh & 15;
  const int g = t >> 4, l15 = t & 15;
  const int j = blockIdx.x * 16 + g;
  const _Float16* kp = kf + (((size_t)bh * 2048 + j) << 6) + l15 * 4;
  float s = 0.f;
#pragma unroll
  for (int i = 0; i < 4; ++i) s += (float)kp[i] * u[h * 64 + l15 * 4 + i];
#pragma unroll
  for (int off = 1; off < 16; off <<= 1) s += __shfl_xor(s, off, 64);
  if (l15 == 0) uk[(size_t)bh * 2048 + j] = s;
}

__global__ __launch_bounds__(256) void vr_dot(
    const _Float16* __restrict__ rf, const float* __restrict__ v,
    float* __restrict__ vr) {
  const int t = threadIdx.x, h = blockIdx.y;
  const int g = t >> 4, l15 = t & 15;
  const int m = blockIdx.x * 16 + g;
  const _Float16* rp = rf + (((size_t)h * 2048 + m) << 6) + l15 * 4;
  float s = 0.f;
#pragma unroll
  for (int i = 0; i < 4; ++i) s += (float)rp[i] * v[h * 64 + l15 * 4 + i];
#pragma unroll
  for (int off = 1; off < 16; off <<= 1) s += __shfl_xor(s, off, 64);
  if (l15 == 0) vr[(size_t)h * 2048 + m] = s;
}

// ---------------------------------------------------------------------------
// MFMA flash attention. Block = (64 q-rows for one (b,h)), 256 thr = 4 waves,
// wave w owns q-rows i0+w*16 .. +15. j-tiles of 64 keys.
// score(i,j) = (q.k + u.k + q.r_m + v.r_m)*0.125, m = j-i+1023,
// mask j > i+1024 (== rel_shift garbage region). Online softmax.
// ---------------------------------------------------------------------------
__global__ __launch_bounds__(256, 2) void attn_mfma(
    const _Float16* __restrict__ qf,   // [bh][1024][64]
    const _Float16* __restrict__ kf,   // [bh][2048][64]
    const _Float16* __restrict__ vfT,  // [bh][64][2048]
    const _Float16* __restrict__ rf,   // [h][2048][64]
    const float* __restrict__ ukw,     // [bh][2048]
    const float* __restrict__ vrw,     // [h][2048]
    _Float16* __restrict__ attn_out)   // [i*4+b][1024] f16
{
  __shared__ _Float16 ks[64 * 64];      // [j][d]
  __shared__ _Float16 vts[64 * 64];     // [d][j]
  __shared__ _Float16 rs[128 * 64];     // [mm][d]
  __shared__ _Float16 Ps[4][16 * 132];  // per-wave (P + vr), [row][mm]
  __shared__ _Float16 pA[4][16 * 64];   // per-wave probs, A-layout [row][jj]
  __shared__ float uks[64];
  __shared__ float vrs[128];

  const int t = threadIdx.x, w = t >> 6, l = t & 63;
  const int l15 = l & 15, l4 = l >> 4;
  const int i0 = blockIdx.x * 64;
  const int bh = blockIdx.y, h = bh & 15, b = bh >> 4;

  // q A-fragments held in registers for the whole loop
  half8 qa0, qa1;
  {
    const _Float16* qrow =
        qf + (((size_t)bh * 1024 + i0 + w * 16 + l15) << 6) + l4 * 8;
    qa0 = *(const half8*)qrow;
    qa1 = *(const half8*)(qrow + 32);
  }
  const f32x4 z4 = {0.f, 0.f, 0.f, 0.f};
  f32x4 o[4];
  o[0] = z4; o[1] = z4; o[2] = z4; o[3] = z4;
  float m_run[4] = {-1e30f, -1e30f, -1e30f, -1e30f};
  float l_run[4] = {0.f, 0.f, 0.f, 0.f};

  const int njt = blockIdx.x + 17;
  for (int jt = 0; jt < njt; ++jt) {
    const int j0 = jt * 64;
    const int m_base = j0 - i0 + 960;
    __syncthreads();
    {
      const char* kg = (const char*)(kf + (((size_t)bh * 2048 + j0) << 6));
      const char* vg = (const char*)(vfT + ((size_t)bh << 17) + j0);
      const char* rg = (const char*)(rf + ((size_t)h << 17));
#pragma unroll
      for (int iss = 0; iss < 2; ++iss) {
        const int off = w * 1024 + iss * 4096 + l * 16;
        load_lds16(kg + off, (char*)ks + w * 1024 + iss * 4096);
        const int d = off >> 7, inner = off & 127;
        load_lds16(vg + (size_t)d * 4096 + inner,
                   (char*)vts + w * 1024 + iss * 4096);
      }
#pragma unroll
      for (int iss = 0; iss < 4; ++iss) {
        const int off = w * 1024 + iss * 4096 + l * 16;
        const int mm = off >> 7, inner = off & 127;
        int m = m_base + mm;
        m = m < 2047 ? m : 2047;
        load_lds16(rg + (size_t)m * 128 + inner,
                   (char*)rs + w * 1024 + iss * 4096);
      }
    }
    if (t < 16)
      *(float4*)&uks[t * 4] = *(const float4*)&ukw[(size_t)bh * 2048 + j0 + t * 4];
    if (t >= 128) {
      const int mm = t - 128;
      int m = m_base + mm;
      m = m < 2047 ? m : 2047;
      vrs[mm] = vrw[h * 2048 + m];
    }
    __syncthreads();

    // content scores S = Q.K^T (16x64 per wave)
    f32x4 sc[4];
#pragma unroll
    for (int nt = 0; nt < 4; ++nt) {
      const half8 b0 = *(const half8*)&ks[((nt * 16 + l15) << 6) + l4 * 8];
      const half8 b1 = *(const half8*)&ks[((nt * 16 + l15) << 6) + 32 + l4 * 8];
      f32x4 c = z4;
      c = __builtin_amdgcn_mfma_f32_16x16x32_f16(qa0, b0, c, 0, 0, 0);
      c = __builtin_amdgcn_mfma_f32_16x16x32_f16(qa1, b1, c, 0, 0, 0);
      sc[nt] = c;
    }
    // position scores over 128-wide r window; fold vr; park in LDS (C layout)
#pragma unroll
    for (int mt = 0; mt < 8; ++mt) {
      const half8 b0 = *(const half8*)&rs[((mt * 16 + l15) << 6) + l4 * 8];
      const half8 b1 = *(const half8*)&rs[((mt * 16 + l15) << 6) + 32 + l4 * 8];
      f32x4 c = z4;
      c = __builtin_amdgcn_mfma_f32_16x16x32_f16(qa0, b0, c, 0, 0, 0);
      c = __builtin_amdgcn_mfma_f32_16x16x32_f16(qa1, b1, c, 0, 0, 0);
      const int mm = mt * 16 + l15;
      const float vradd = vrs[mm];
#pragma unroll
      for (int r = 0; r < 4; ++r)
        Ps[w][(l4 * 4 + r) * 132 + mm] = (_Float16)(c[r] + vradd);
    }

    // parallel online softmax (each lane: 4 rows x 4 cols)
    float uk4[4];
#pragma unroll
    for (int nt = 0; nt < 4; ++nt) uk4[nt] = uks[nt * 16 + l15];
    float alpha[4];
#pragma unroll
    for (int r = 0; r < 4; ++r) {
      const int iloc = w * 16 + l4 * 4 + r;
      float sv[4];
      float mx = -1e30f;
#pragma unroll
      for (int nt = 0; nt < 4; ++nt) {
        const int jj = nt * 16 + l15;
        const int mm = jj - iloc + 63;
        const float pval = (float)Ps[w][(l4 * 4 + r) * 132 + mm];
        float s = (sc[nt][r] + uk4[nt] + pval) * 0.125f;
        if (j0 + jj > i0 + iloc + 1024) s = -1e30f;
        sv[nt] = s;
        mx = fmaxf(mx, s);
      }
#pragma unroll
      for (int off = 1; off < 16; off <<= 1)
        mx = fmaxf(mx, __shfl_xor(mx, off, 64));
      const float mnew = fmaxf(m_run[r], mx);
      const float a = __expf(m_run[r] - mnew);
      float esum = 0.f;
#pragma unroll
      for (int nt = 0; nt < 4; ++nt) {
        const float e = __expf(sv[nt] - mnew);
        esum += e;
        pA[w][(l4 * 4 + r) * 64 + nt * 16 + l15] = (_Float16)e;
      }
#pragma unroll
      for (int off = 1; off < 16; off <<= 1) esum += __shfl_xor(esum, off, 64);
      l_run[r] = l_run[r] * a + esum;
      m_run[r] = mnew;
      alpha[r] = a;
    }
#pragma unroll
    for (int nt = 0; nt < 4; ++nt) {
      f32x4 oo = o[nt];
      oo[0] *= alpha[0]; oo[1] *= alpha[1];
      oo[2] *= alpha[2]; oo[3] *= alpha[3];
      o[nt] = oo;
    }
    // PV: O += P.V  (A from pA, B from vts = V^T rows)
#pragma unroll
    for (int kk = 0; kk < 2; ++kk) {
      const half8 a8 = *(const half8*)&pA[w][(l15 << 6) + kk * 32 + l4 * 8];
#pragma unroll
      for (int nt = 0; nt < 4; ++nt) {
        const half8 b8 =
            *(const half8*)&vts[((nt * 16 + l15) << 6) + kk * 32 + l4 * 8];
        o[nt] = __builtin_amdgcn_mfma_f32_16x16x32_f16(a8, b8, o[nt], 0, 0, 0);
      }
    }
  }

#pragma unroll
  for (int r = 0; r < 4; ++r) {
    const float inv = 1.0f / l_run[r];
    const int i = i0 + w * 16 + l4 * 4 + r;
    const size_t base = ((size_t)i * 4 + b) * 1024 + h * 64;
#pragma unroll
    for (int nt = 0; nt < 4; ++nt)
      attn_out[base + nt * 16 + l15] = (_Float16)(o[nt][r] * inv);
  }
}

// ---------------------------------------------------------------------------
extern "C" void kernel_launch(void* const* d_in, const int* in_sizes, int n_in,
                              void* d_out, int out_size, void* d_ws,
                              size_t ws_size, hipStream_t stream) {
  const float* inputs   = (const float*)d_in[0];
  const float* pos_emb  = (const float*)d_in[1];
  const float* full_inp = (const float*)d_in[2];
  const float* u        = (const float*)d_in[3];
  const float* v        = (const float*)d_in[4];
  const float* W_kv   = (const float*)d_in[6];
  const float* b_kv   = (const float*)d_in[7];
  const float* W_q    = (const float*)d_in[8];
  const float* b_q    = (const float*)d_in[9];
  const float* W_pos  = (const float*)d_in[10];
  const float* b_pos  = (const float*)d_in[11];
  const float* W_proj = (const float*)d_in[12];
  const float* b_proj = (const float*)d_in[13];
  float* out = (float*)d_out;

  char* ws = (char*)d_ws;
  const size_t MB = 1024 * 1024;
  _Float16* in_q_h    = (_Float16*)(ws);            // 8 MB  (4096x1024)
  _Float16* in_full_h = (_Float16*)(ws + 8 * MB);   // 16 MB (8192x1024)
  _Float16* in_pos_h  = (_Float16*)(ws + 24 * MB);  // 4 MB  (2048x1024)
  _Float16* attn_h    = (_Float16*)(ws + 28 * MB);  // 8 MB  (4096x1024)
  _Float16* wq_t      = (_Float16*)(ws + 36 * MB);  // 2 MB  (1024x1024)
  _Float16* wkv_t     = (_Float16*)(ws + 38 * MB);  // 4 MB  (2048x1024)
  _Float16* wpos_t    = (_Float16*)(ws + 42 * MB);  // 2 MB
  _Float16* wproj_t   = (_Float16*)(ws + 44 * MB);  // 2 MB
  _Float16* qf        = (_Float16*)(ws + 46 * MB);  // 8 MB  [bh][1024][64]
  _Float16* kf        = (_Float16*)(ws + 54 * MB);  // 16 MB [bh][2048][64]
  _Float16* vfT       = (_Float16*)(ws + 70 * MB);  // 16 MB [bh][64][2048]
  _Float16* rf        = (_Float16*)(ws + 86 * MB);  // 4 MB  [h][2048][64]
  float* uk_ws        = (float*)(ws + 90 * MB);     // 32 KB [bh][2048]
  float* vr_ws        = (float*)(ws + 90 * MB + 32 * 1024);  // 128 KB [h][2048]

  const dim3 blk(256);
  f32_to_f16<<<dim3(4096), blk, 0, stream>>>(inputs, in_q_h, 1048576);
  f32_to_f16<<<dim3(8192), blk, 0, stream>>>(full_inp, in_full_h, 2097152);
  f32_to_f16<<<dim3(2048), blk, 0, stream>>>(pos_emb, in_pos_h, 524288);
  wt_f16<<<dim3(16, 16), blk, 0, stream>>>(W_q, wq_t, 1024, 1024);
  wt_f16<<<dim3(32, 16), blk, 0, stream>>>(W_kv, wkv_t, 1024, 2048);
  wt_f16<<<dim3(16, 16), blk, 0, stream>>>(W_pos, wpos_t, 1024, 1024);
  wt_f16<<<dim3(16, 16), blk, 0, stream>>>(W_proj, wproj_t, 1024, 1024);

  gemm_f16<1><<<dim3(8, 32), blk, 0, stream>>>(in_q_h, wq_t, b_q, qf, nullptr,
                                               4096, 1024, 1024);
  gemm_f16<2><<<dim3(16, 64), blk, 0, stream>>>(in_full_h, wkv_t, b_kv, kf,
                                                vfT, 8192, 2048, 1024);
  gemm_f16<3><<<dim3(8, 16), blk, 0, stream>>>(in_pos_h, wpos_t, b_pos, rf,
                                               nullptr, 2048, 1024, 1024);
  uk_dot<<<dim3(128, 64), blk, 0, stream>>>(kf, u, uk_ws);
  vr_dot<<<dim3(128, 16), blk, 0, stream>>>(rf, v, vr_ws);

  attn_mfma<<<dim3(16, 64), blk, 0, stream>>>(qf, kf, vfT, rf, uk_ws, vr_ws,
                                              attn_h);

  gemm_f16<0><<<dim3(8, 32), blk, 0, stream>>>(attn_h, wproj_t, b_proj, out,
                                               nullptr, 4096, 1024, 1024);
}

// Round 3
// 420.337 us; speedup vs baseline: 10.9413x; 1.3727x over previous
//
#include <hip/hip_runtime.h>

// AttentionXL: CUR=1024, FULL=2048, BS=4, D=1024, HN=16, HD=64, PREV=1024
// f16 MFMA 16x16x32 everywhere; fp32 accumulate/softmax.

typedef _Float16 half8 __attribute__((ext_vector_type(8)));
typedef _Float16 half4v __attribute__((ext_vector_type(4)));
typedef float f32x4 __attribute__((ext_vector_type(4)));

typedef const __attribute__((address_space(1))) void* gas_ptr;
typedef __attribute__((address_space(3))) void* las_ptr;

__device__ __forceinline__ void load_lds16(const void* g, void* l) {
  __builtin_amdgcn_global_load_lds((gas_ptr)g, (las_ptr)l, 16, 0, 0);
}

// ---------------------------------------------------------------------------
// fused fp32 -> f16 for the three activations (inputs / full_input / pos_emb)
// ---------------------------------------------------------------------------
__global__ __launch_bounds__(256) void cvt_all(
    const float* __restrict__ a, const float* __restrict__ b,
    const float* __restrict__ c, _Float16* __restrict__ oa,
    _Float16* __restrict__ ob, _Float16* __restrict__ oc) {
  size_t g = (size_t)blockIdx.x * 256 + threadIdx.x;  // float4-group id
  const float* src;
  _Float16* dst;
  size_t idx;
  if (g < (1u << 20)) {
    src = a; dst = oa; idx = g;
  } else if (g < (3u << 20)) {
    src = b; dst = ob; idx = g - (1u << 20);
  } else {
    src = c; dst = oc; idx = g - (3u << 20);
  }
  float4 v = *(const float4*)(src + idx * 4);
  half4v h;
  h[0] = (_Float16)v.x; h[1] = (_Float16)v.y;
  h[2] = (_Float16)v.z; h[3] = (_Float16)v.w;
  *(half4v*)(dst + idx * 4) = h;
}

// ---------------------------------------------------------------------------
// fused weight convert+transpose: W f32 [K][N] -> Wt f16 [N][K], 64x64 tiles.
// ---------------------------------------------------------------------------
__global__ __launch_bounds__(256) void wt_all(
    const float* __restrict__ Wq, const float* __restrict__ Wkv,
    const float* __restrict__ Wpos, const float* __restrict__ Wproj,
    _Float16* __restrict__ oq, _Float16* __restrict__ okv,
    _Float16* __restrict__ opos, _Float16* __restrict__ oproj) {
  __shared__ _Float16 tile[64][65];
  const int bx = blockIdx.x;
  const float* W;
  _Float16* Wt;
  int N, tidx;
  if (bx < 256) { W = Wq; Wt = oq; N = 1024; tidx = bx; }
  else if (bx < 768) { W = Wkv; Wt = okv; N = 2048; tidx = bx - 256; }
  else if (bx < 1024) { W = Wpos; Wt = opos; N = 1024; tidx = bx - 768; }
  else { W = Wproj; Wt = oproj; N = 1024; tidx = bx - 1024; }
  const int K = 1024;
  const int n0 = (tidx % (N >> 6)) * 64, k0 = (tidx / (N >> 6)) * 64;
  const int t = threadIdx.x;
  const int rr = t >> 2, cc = (t & 3) * 16;
#pragma unroll
  for (int i = 0; i < 4; ++i) {
    float4 v = *(const float4*)&W[(size_t)(k0 + rr) * N + n0 + cc + i * 4];
    tile[rr][cc + i * 4 + 0] = (_Float16)v.x;
    tile[rr][cc + i * 4 + 1] = (_Float16)v.y;
    tile[rr][cc + i * 4 + 2] = (_Float16)v.z;
    tile[rr][cc + i * 4 + 3] = (_Float16)v.w;
  }
  __syncthreads();
  const int n = t >> 2, kc = (t & 3) * 16;
#pragma unroll
  for (int i = 0; i < 4; ++i) {
    half4v h;
    h[0] = tile[kc + i * 4 + 0][n];
    h[1] = tile[kc + i * 4 + 1][n];
    h[2] = tile[kc + i * 4 + 2][n];
    h[3] = tile[kc + i * 4 + 3][n];
    *(half4v*)&Wt[(size_t)(n0 + n) * K + k0 + kc + i * 4] = h;
  }
}

// ---------------------------------------------------------------------------
// f16 MFMA GEMM: C[M][N] = A[M][K] @ Bt[N][K]^T + bias.  128x128x32 tiles.
// MODE 0: f32 row-major; 1: qf[bh][i][d]; 2: kf[bh][j][d] + vfT[bh][d][j];
// MODE 3: rf[h][m][d]
// ---------------------------------------------------------------------------
template <int MODE>
__global__ __launch_bounds__(256, 2) void gemm_f16(
    const _Float16* __restrict__ A, const _Float16* __restrict__ Bt,
    const float* __restrict__ bias, void* __restrict__ out0,
    void* __restrict__ out1, int M, int N, int K) {
  __shared__ _Float16 As[128 * 32];
  __shared__ _Float16 Bs[128 * 32];
  const int t = threadIdx.x, w = t >> 6, l = t & 63;
  const int l15 = l & 15, l4 = l >> 4;
  const int bm = blockIdx.y * 128, bn = blockIdx.x * 128;
  const int wm = (w >> 1) * 64, wn = (w & 1) * 64;

  f32x4 acc[4][4];
  const f32x4 z4 = {0.f, 0.f, 0.f, 0.f};
#pragma unroll
  for (int i = 0; i < 4; ++i)
#pragma unroll
    for (int j = 0; j < 4; ++j) acc[i][j] = z4;

  const char* Abase = (const char*)A + (size_t)bm * K * 2;
  const char* Bbase = (const char*)Bt + (size_t)bn * K * 2;
  char* Asl = (char*)As;
  char* Bsl = (char*)Bs;

  for (int k0 = 0; k0 < K; k0 += 32) {
    __syncthreads();
#pragma unroll
    for (int iss = 0; iss < 2; ++iss) {
      const int off = w * 1024 + iss * 4096 + l * 16;
      const int row = off >> 6, kb = off & 63;
      load_lds16(Abase + (size_t)row * (K * 2) + k0 * 2 + kb,
                 Asl + w * 1024 + iss * 4096);
      load_lds16(Bbase + (size_t)row * (K * 2) + k0 * 2 + kb,
                 Bsl + w * 1024 + iss * 4096);
    }
    __syncthreads();
    half8 af[4], bf[4];
#pragma unroll
    for (int mt = 0; mt < 4; ++mt)
      af[mt] = *(const half8*)&As[(wm + mt * 16 + l15) * 32 + l4 * 8];
#pragma unroll
    for (int nt = 0; nt < 4; ++nt)
      bf[nt] = *(const half8*)&Bs[(wn + nt * 16 + l15) * 32 + l4 * 8];
#pragma unroll
    for (int mt = 0; mt < 4; ++mt)
#pragma unroll
      for (int nt = 0; nt < 4; ++nt)
        acc[mt][nt] = __builtin_amdgcn_mfma_f32_16x16x32_f16(
            af[mt], bf[nt], acc[mt][nt], 0, 0, 0);
  }

#pragma unroll
  for (int mt = 0; mt < 4; ++mt)
#pragma unroll
    for (int r = 0; r < 4; ++r) {
      const int row = bm + wm + mt * 16 + l4 * 4 + r;
#pragma unroll
      for (int nt = 0; nt < 4; ++nt) {
        const int col = bn + wn + nt * 16 + l15;
        const float val = acc[mt][nt][r] + bias[col];
        if (MODE == 0) {
          ((float*)out0)[(size_t)row * N + col] = val;
        } else if (MODE == 1) {
          const int i = row >> 2, b = row & 3, h = col >> 6, d = col & 63;
          ((_Float16*)out0)[(((size_t)(b * 16 + h) * 1024 + i) << 6) + d] =
              (_Float16)val;
        } else if (MODE == 2) {
          const int j = row >> 2, b = row & 3;
          const int c = col & 1023, h = c >> 6, d = c & 63;
          if ((col >> 10) == 0)
            ((_Float16*)out0)[(((size_t)(b * 16 + h) * 2048 + j) << 6) + d] =
                (_Float16)val;
          else
            ((_Float16*)out1)[(((size_t)(b * 16 + h) * 64 + d) << 11) + j] =
                (_Float16)val;
        } else {
          const int h = col >> 6, d = col & 63;
          ((_Float16*)out0)[(((size_t)h * 2048 + row) << 6) + d] = (_Float16)val;
        }
      }
    }
}

// ---------------------------------------------------------------------------
// fused uk[bh][j] = u_h . k  and  vr[h][m] = v_h . r
// ---------------------------------------------------------------------------
__global__ __launch_bounds__(256) void ukvr_dot(
    const _Float16* __restrict__ kf, const _Float16* __restrict__ rf,
    const float* __restrict__ u, const float* __restrict__ v,
    float* __restrict__ uk, float* __restrict__ vr) {
  const int t = threadIdx.x, by = blockIdx.y;
  const int g = t >> 4, l15 = t & 15;
  const int row = blockIdx.x * 16 + g;
  const _Float16* mat;
  const float* uv;
  float* out;
  int h;
  if (by < 64) {
    h = by & 15;
    mat = kf + (((size_t)by * 2048 + row) << 6);
    uv = u; out = uk + (size_t)by * 2048 + row;
  } else {
    h = by - 64;
    mat = rf + (((size_t)h * 2048 + row) << 6);
    uv = v; out = vr + (size_t)h * 2048 + row;
  }
  float s = 0.f;
#pragma unroll
  for (int i = 0; i < 4; ++i)
    s += (float)mat[l15 * 4 + i] * uv[h * 64 + l15 * 4 + i];
#pragma unroll
  for (int off = 1; off < 16; off <<= 1) s += __shfl_xor(s, off, 64);
  if (l15 == 0) *out = s;
}

// ---------------------------------------------------------------------------
// MFMA flash attention v2.
//  - XOR-swizzled LDS (chunk ^= row&7, swizzle applied on global src address
//    so global_load_lds dest stays linear).
//  - position window: 5 tiles/wave (79 needed), fp32 shuffle-gather (no LDS
//    park, no f16 rounding of position scores).
//  - no online max (logits bounded): plain exp, deferred row-sum.
//  - rs/vrs are 128-row ring buffers; only 64 new rows staged per j-tile.
// ---------------------------------------------------------------------------
__global__ __launch_bounds__(256, 3) void attn_mfma(
    const _Float16* __restrict__ qf,   // [bh][1024][64]
    const _Float16* __restrict__ kf,   // [bh][2048][64]
    const _Float16* __restrict__ vfT,  // [bh][64][2048]
    const _Float16* __restrict__ rf,   // [h][2048][64]
    const float* __restrict__ ukw,     // [bh][2048]
    const float* __restrict__ vrw,     // [h][2048]
    _Float16* __restrict__ attn_out)   // [i*4+b][1024] f16
{
  __shared__ _Float16 ks[64 * 64];   // [j][d] swizzled
  __shared__ _Float16 vts[64 * 64];  // [d][j] swizzled
  __shared__ _Float16 rs[128 * 64];  // ring of r rows, swizzled
  __shared__ _Float16 pA[4][16 * 70];  // per-wave probs, A-layout, padded
  __shared__ float uks[64];
  __shared__ float vrs[128];  // ring

  const int t = threadIdx.x, w = t >> 6, l = t & 63;
  const int l15 = l & 15, l4 = l >> 4;
  const int i0 = blockIdx.x * 64;
  const int bh = blockIdx.y, h = bh & 15, b = bh >> 4;

  const char* kfb = (const char*)(kf + (((size_t)bh * 2048) << 6));
  const char* vg = (const char*)(vfT + (((size_t)bh) << 17));
  const char* rg = (const char*)(rf + (((size_t)h) << 17));

  // q A-fragments in registers for the whole loop
  half8 qa0, qa1;
  {
    const _Float16* qrow =
        qf + (((size_t)bh * 1024 + i0 + w * 16 + l15) << 6) + l4 * 8;
    qa0 = *(const half8*)qrow;
    qa1 = *(const half8*)(qrow + 32);
  }
  const f32x4 z4 = {0.f, 0.f, 0.f, 0.f};
  f32x4 o[4];
  o[0] = z4; o[1] = z4; o[2] = z4; o[3] = z4;
  float lsum[4] = {0.f, 0.f, 0.f, 0.f};

  // ---- prologue: stage full 128-row r window (slot = m & 127) ----
  const int mb0 = 960 - i0;  // m_base at jt=0 (>= 0)
  {
    const int base0 = mb0 & 127;
#pragma unroll
    for (int iss = 0; iss < 4; ++iss) {
      const int off = w * 1024 + iss * 4096 + l * 16;
      const int slot = off >> 7;
      const int cph = (off >> 4) & 7;
      int m = mb0 + ((slot - base0) & 127);
      m = m < 2047 ? m : 2047;
      load_lds16(rg + (size_t)m * 128 + ((cph ^ (slot & 7)) << 4),
                 (char*)rs + off);
    }
    if (t < 128) {
      int m = mb0 + ((t - base0) & 127);
      m = m < 2047 ? m : 2047;
      vrs[t] = vrw[h * 2048 + m];
    }
  }

  const int njt = blockIdx.x + 17;
  for (int jt = 0; jt < njt; ++jt) {
    const int j0 = jt * 64;
    const int m_base = j0 - i0 + 960;
    __syncthreads();  // prior tile's reads done before overwrite
    // ---- stage K, V^T (swizzled source) ----
    {
      const char* kg = kfb + (size_t)j0 * 128;
#pragma unroll
      for (int iss = 0; iss < 2; ++iss) {
        const int off = w * 1024 + iss * 4096 + l * 16;
        const int row = off >> 7;
        const int cph = (off >> 4) & 7;
        const int sw = ((cph ^ (row & 7)) << 4);
        load_lds16(kg + (size_t)row * 128 + sw, (char*)ks + off);
        load_lds16(vg + (size_t)row * 4096 + (size_t)j0 * 2 + sw,
                   (char*)vts + off);
      }
    }
    // ---- stage 64 new r rows into the ring ----
    if (jt > 0) {
      const int sb = (m_base + 64) & 127;  // 0 or 64 (contiguous slots)
#pragma unroll
      for (int iss = 0; iss < 2; ++iss) {
        const int off = w * 1024 + iss * 4096 + l * 16;
        const int q = off >> 7;
        const int cph = (off >> 4) & 7;
        const int slot = sb + q;
        int m = m_base + 64 + q;
        m = m < 2047 ? m : 2047;
        load_lds16(rg + (size_t)m * 128 + ((cph ^ (slot & 7)) << 4),
                   (char*)rs + slot * 128 + cph * 16);
      }
      if (t >= 128 && t < 192) {
        const int q = t - 128;
        int m = m_base + 64 + q;
        m = m < 2047 ? m : 2047;
        vrs[sb + q] = vrw[h * 2048 + m];
      }
    }
    if (t < 16)
      *(float4*)&uks[t * 4] =
          *(const float4*)&ukw[(size_t)bh * 2048 + j0 + t * 4];
    __syncthreads();

    // ---- content scores S = Q.K^T (16x64 per wave) ----
    f32x4 sc[4];
#pragma unroll
    for (int nt = 0; nt < 4; ++nt) {
      const int row = nt * 16 + l15;
      const int rsw = row & 7;
      const half8 b0 = *(const half8*)&ks[row * 64 + ((l4 ^ rsw) * 8)];
      const half8 b1 = *(const half8*)&ks[row * 64 + (((4 + l4) ^ rsw) * 8)];
      f32x4 cc = z4;
      cc = __builtin_amdgcn_mfma_f32_16x16x32_f16(qa0, b0, cc, 0, 0, 0);
      cc = __builtin_amdgcn_mfma_f32_16x16x32_f16(qa1, b1, cc, 0, 0, 0);
      sc[nt] = cc;
    }
    // ---- position scores: 5 tiles covering this wave's 79-wide window ----
    f32x4 accP[5];
#pragma unroll
    for (int p = 0; p < 5; ++p) {
      const int m = m_base + (3 - w + p) * 16 + l15;
      const int slot = m & 127;
      const int ssw = slot & 7;
      const half8 b0 = *(const half8*)&rs[slot * 64 + ((l4 ^ ssw) * 8)];
      const half8 b1 = *(const half8*)&rs[slot * 64 + (((4 + l4) ^ ssw) * 8)];
      f32x4 cc = z4;
      cc = __builtin_amdgcn_mfma_f32_16x16x32_f16(qa0, b0, cc, 0, 0, 0);
      cc = __builtin_amdgcn_mfma_f32_16x16x32_f16(qa1, b1, cc, 0, 0, 0);
      accP[p] = cc;
    }
    float vr_reg[5];
#pragma unroll
    for (int p = 0; p < 5; ++p) {
      const int m = m_base + (3 - w + p) * 16 + l15;
      vr_reg[p] = vrs[m & 127];
    }
    float uk4[4];
#pragma unroll
    for (int nt = 0; nt < 4; ++nt) uk4[nt] = uks[nt * 16 + l15];

    // ---- softmax (no max subtraction; logits bounded) + P in A-layout ----
    const int cw = i0 - j0 + 1024 + 16 * w;  // mask: jl > cw + (4*l4+r)
#pragma unroll
    for (int r = 0; r < 4; ++r) {
      const int thr = 4 * l4 + r;
      const int srcl = (l4 << 4) | ((15 + l15 - thr) & 15);
      float rot[5];
#pragma unroll
      for (int p = 0; p < 5; ++p)
        rot[p] = __shfl(accP[p][r] + vr_reg[p], srcl, 64);
      float esum = 0.f;
#pragma unroll
      for (int nt = 0; nt < 4; ++nt) {
        const float pv = (l15 <= thr) ? rot[nt] : rot[nt + 1];
        const float s = (sc[nt][r] + uk4[nt] + pv) * 0.125f;
        const bool masked = (16 * nt + l15) > (cw + thr);
        const float e = masked ? 0.f : __expf(s);
        esum += e;
        pA[w][(thr)*70 + 16 * nt + l15] = (_Float16)e;
      }
      lsum[r] += esum;
    }
    // ---- PV: O += P.V ----
#pragma unroll
    for (int kk = 0; kk < 2; ++kk) {
      const half8 a8 = *(const half8*)&pA[w][l15 * 70 + kk * 32 + l4 * 8];
#pragma unroll
      for (int nt = 0; nt < 4; ++nt) {
        const int row = nt * 16 + l15;
        const half8 b8 =
            *(const half8*)&vts[row * 64 + ((((kk << 2) + l4) ^ (row & 7)) * 8)];
        o[nt] = __builtin_amdgcn_mfma_f32_16x16x32_f16(a8, b8, o[nt], 0, 0, 0);
      }
    }
  }

  // ---- epilogue: row-sum across the 16-lane group, normalize, store ----
#pragma unroll
  for (int r = 0; r < 4; ++r) {
    float s = lsum[r];
    s += __shfl_xor(s, 1, 64);
    s += __shfl_xor(s, 2, 64);
    s += __shfl_xor(s, 4, 64);
    s += __shfl_xor(s, 8, 64);
    const float inv = 1.0f / s;
    const int i = i0 + w * 16 + l4 * 4 + r;
    const size_t base = ((size_t)i * 4 + b) * 1024 + h * 64;
#pragma unroll
    for (int nt = 0; nt < 4; ++nt)
      attn_out[base + nt * 16 + l15] = (_Float16)(o[nt][r] * inv);
  }
}

// ---------------------------------------------------------------------------
extern "C" void kernel_launch(void* const* d_in, const int* in_sizes, int n_in,
                              void* d_out, int out_size, void* d_ws,
                              size_t ws_size, hipStream_t stream) {
  const float* inputs   = (const float*)d_in[0];
  const float* pos_emb  = (const float*)d_in[1];
  const float* full_inp = (const float*)d_in[2];
  const float* u        = (const float*)d_in[3];
  const float* v        = (const float*)d_in[4];
  const float* W_kv   = (const float*)d_in[6];
  const float* b_kv   = (const float*)d_in[7];
  const float* W_q    = (const float*)d_in[8];
  const float* b_q    = (const float*)d_in[9];
  const float* W_pos  = (const float*)d_in[10];
  const float* b_pos  = (const float*)d_in[11];
  const float* W_proj = (const float*)d_in[12];
  const float* b_proj = (const float*)d_in[13];
  float* out = (float*)d_out;

  char* ws = (char*)d_ws;
  const size_t MB = 1024 * 1024;
  _Float16* in_q_h    = (_Float16*)(ws);            // 8 MB  (4096x1024)
  _Float16* in_full_h = (_Float16*)(ws + 8 * MB);   // 16 MB (8192x1024)
  _Float16* in_pos_h  = (_Float16*)(ws + 24 * MB);  // 4 MB  (2048x1024)
  _Float16* attn_h    = (_Float16*)(ws + 28 * MB);  // 8 MB  (4096x1024)
  _Float16* wq_t      = (_Float16*)(ws + 36 * MB);  // 2 MB  (1024x1024)
  _Float16* wkv_t     = (_Float16*)(ws + 38 * MB);  // 4 MB  (2048x1024)
  _Float16* wpos_t    = (_Float16*)(ws + 42 * MB);  // 2 MB
  _Float16* wproj_t   = (_Float16*)(ws + 44 * MB);  // 2 MB
  _Float16* qf        = (_Float16*)(ws + 46 * MB);  // 8 MB  [bh][1024][64]
  _Float16* kf        = (_Float16*)(ws + 54 * MB);  // 16 MB [bh][2048][64]
  _Float16* vfT       = (_Float16*)(ws + 70 * MB);  // 16 MB [bh][64][2048]
  _Float16* rf        = (_Float16*)(ws + 86 * MB);  // 4 MB  [h][2048][64]
  float* uk_ws        = (float*)(ws + 90 * MB);     // 512 KB [bh][2048]
  float* vr_ws        = (float*)(ws + 91 * MB);     // 128 KB [h][2048]

  const dim3 blk(256);
  cvt_all<<<dim3(14336), blk, 0, stream>>>(inputs, full_inp, pos_emb, in_q_h,
                                           in_full_h, in_pos_h);
  wt_all<<<dim3(1280), blk, 0, stream>>>(W_q, W_kv, W_pos, W_proj, wq_t, wkv_t,
                                         wpos_t, wproj_t);

  gemm_f16<1><<<dim3(8, 32), blk, 0, stream>>>(in_q_h, wq_t, b_q, qf, nullptr,
                                               4096, 1024, 1024);
  gemm_f16<2><<<dim3(16, 64), blk, 0, stream>>>(in_full_h, wkv_t, b_kv, kf,
                                                vfT, 8192, 2048, 1024);
  gemm_f16<3><<<dim3(8, 16), blk, 0, stream>>>(in_pos_h, wpos_t, b_pos, rf,
                                               nullptr, 2048, 1024, 1024);
  ukvr_dot<<<dim3(128, 80), blk, 0, stream>>>(kf, rf, u, v, uk_ws, vr_ws);

  attn_mfma<<<dim3(16, 64), blk, 0, stream>>>(qf, kf, vfT, rf, uk_ws, vr_ws,
                                              attn_h);

  gemm_f16<0><<<dim3(8, 32), blk, 0, stream>>>(attn_h, wproj_t, b_proj, out,
                                               nullptr, 4096, 1024, 1024);
}

// Round 4
// 420.076 us; speedup vs baseline: 10.9481x; 1.0006x over previous
//
#include <hip/hip_runtime.h>

// AttentionXL: CUR=1024, FULL=2048, BS=4, D=1024, HN=16, HD=64, PREV=1024
// f16 MFMA 16x16x32 everywhere; fp32 accumulate/softmax.

typedef _Float16 half8 __attribute__((ext_vector_type(8)));
typedef _Float16 half4v __attribute__((ext_vector_type(4)));
typedef float f32x4 __attribute__((ext_vector_type(4)));

typedef const __attribute__((address_space(1))) void* gas_ptr;
typedef __attribute__((address_space(3))) void* las_ptr;

__device__ __forceinline__ void load_lds16(const void* g, void* l) {
  __builtin_amdgcn_global_load_lds((gas_ptr)g, (las_ptr)l, 16, 0, 0);
}

// ---------------------------------------------------------------------------
// fused prep: fp32->f16 converts (blocks [0,14336)) + weight transpose
// (blocks [14336,15616)).
// ---------------------------------------------------------------------------
__global__ __launch_bounds__(256) void prep(
    const float* __restrict__ inputs, const float* __restrict__ full_inp,
    const float* __restrict__ pos_emb, const float* __restrict__ Wq,
    const float* __restrict__ Wkv, const float* __restrict__ Wpos,
    const float* __restrict__ Wproj, _Float16* __restrict__ o_in,
    _Float16* __restrict__ o_full, _Float16* __restrict__ o_pos,
    _Float16* __restrict__ owq, _Float16* __restrict__ owkv,
    _Float16* __restrict__ owpos, _Float16* __restrict__ owproj) {
  __shared__ _Float16 tile[64][65];
  const int bx = blockIdx.x;
  const int t = threadIdx.x;
  if (bx < 14336) {
    size_t g = (size_t)bx * 256 + t;  // float4-group id
    const float* src;
    _Float16* dst;
    size_t idx;
    if (g < (1u << 20)) {
      src = inputs; dst = o_in; idx = g;
    } else if (g < (3u << 20)) {
      src = full_inp; dst = o_full; idx = g - (1u << 20);
    } else {
      src = pos_emb; dst = o_pos; idx = g - (3u << 20);
    }
    float4 v = *(const float4*)(src + idx * 4);
    half4v h;
    h[0] = (_Float16)v.x; h[1] = (_Float16)v.y;
    h[2] = (_Float16)v.z; h[3] = (_Float16)v.w;
    *(half4v*)(dst + idx * 4) = h;
    return;
  }
  const int wb = bx - 14336;
  const float* W;
  _Float16* Wt;
  int N, tidx;
  if (wb < 256) { W = Wq; Wt = owq; N = 1024; tidx = wb; }
  else if (wb < 768) { W = Wkv; Wt = owkv; N = 2048; tidx = wb - 256; }
  else if (wb < 1024) { W = Wpos; Wt = owpos; N = 1024; tidx = wb - 768; }
  else { W = Wproj; Wt = owproj; N = 1024; tidx = wb - 1024; }
  const int K = 1024;
  const int n0 = (tidx % (N >> 6)) * 64, k0 = (tidx / (N >> 6)) * 64;
  const int rr = t >> 2, cc = (t & 3) * 16;
#pragma unroll
  for (int i = 0; i < 4; ++i) {
    float4 v = *(const float4*)&W[(size_t)(k0 + rr) * N + n0 + cc + i * 4];
    tile[rr][cc + i * 4 + 0] = (_Float16)v.x;
    tile[rr][cc + i * 4 + 1] = (_Float16)v.y;
    tile[rr][cc + i * 4 + 2] = (_Float16)v.z;
    tile[rr][cc + i * 4 + 3] = (_Float16)v.w;
  }
  __syncthreads();
  const int n = t >> 2, kc = (t & 3) * 16;
#pragma unroll
  for (int i = 0; i < 4; ++i) {
    half4v h;
    h[0] = tile[kc + i * 4 + 0][n];
    h[1] = tile[kc + i * 4 + 1][n];
    h[2] = tile[kc + i * 4 + 2][n];
    h[3] = tile[kc + i * 4 + 3][n];
    *(half4v*)&Wt[(size_t)(n0 + n) * K + k0 + kc + i * 4] = h;
  }
}

// ---------------------------------------------------------------------------
// Fused q/kv/r GEMM: one dispatch, 1408 blocks.
//   [0,256):    q    4096x1024x1024 -> qf[bh][i][d]
//   [256,1280): kv   8192x2048x1024 -> kf[bh][j][d] + vfT[bh][d][j]
//   [1280,1408): r   2048x1024x1024 -> rf[h][m][d]
// 128x128x32 tiles, 256 thr = 2x2 waves, 4x4 MFMA tiles each.
// ---------------------------------------------------------------------------
__global__ __launch_bounds__(256, 2) void gemm3(
    const _Float16* __restrict__ Aq, const _Float16* __restrict__ Akv,
    const _Float16* __restrict__ Ar, const _Float16* __restrict__ Btq,
    const _Float16* __restrict__ Btkv, const _Float16* __restrict__ Btr,
    const float* __restrict__ bq, const float* __restrict__ bkv,
    const float* __restrict__ br, _Float16* __restrict__ qf,
    _Float16* __restrict__ kf, _Float16* __restrict__ vfT,
    _Float16* __restrict__ rf) {
  __shared__ _Float16 As[128 * 32];
  __shared__ _Float16 Bs[128 * 32];
  const int gb = blockIdx.x;
  const _Float16* A;
  const _Float16* Bt;
  const float* bias;
  int mode, bm, bn;
  if (gb < 256) {
    mode = 1; A = Aq; Bt = Btq; bias = bq;
    bn = (gb & 7) * 128; bm = (gb >> 3) * 128;
  } else if (gb < 1280) {
    mode = 2; A = Akv; Bt = Btkv; bias = bkv;
    const int j = gb - 256;
    bn = (j & 15) * 128; bm = (j >> 4) * 128;
  } else {
    mode = 3; A = Ar; Bt = Btr; bias = br;
    const int j = gb - 1280;
    bn = (j & 7) * 128; bm = (j >> 3) * 128;
  }
  const int K = 1024;
  const int t = threadIdx.x, w = t >> 6, l = t & 63;
  const int l15 = l & 15, l4 = l >> 4;
  const int wm = (w >> 1) * 64, wn = (w & 1) * 64;

  f32x4 acc[4][4];
  const f32x4 z4 = {0.f, 0.f, 0.f, 0.f};
#pragma unroll
  for (int i = 0; i < 4; ++i)
#pragma unroll
    for (int j = 0; j < 4; ++j) acc[i][j] = z4;

  const char* Abase = (const char*)A + (size_t)bm * K * 2;
  const char* Bbase = (const char*)Bt + (size_t)bn * K * 2;
  char* Asl = (char*)As;
  char* Bsl = (char*)Bs;

  for (int k0 = 0; k0 < K; k0 += 32) {
    __syncthreads();
#pragma unroll
    for (int iss = 0; iss < 2; ++iss) {
      const int off = w * 1024 + iss * 4096 + l * 16;
      const int row = off >> 6, kb = off & 63;
      load_lds16(Abase + (size_t)row * (K * 2) + k0 * 2 + kb,
                 Asl + w * 1024 + iss * 4096);
      load_lds16(Bbase + (size_t)row * (K * 2) + k0 * 2 + kb,
                 Bsl + w * 1024 + iss * 4096);
    }
    __syncthreads();
    half8 af[4], bf[4];
#pragma unroll
    for (int mt = 0; mt < 4; ++mt)
      af[mt] = *(const half8*)&As[(wm + mt * 16 + l15) * 32 + l4 * 8];
#pragma unroll
    for (int nt = 0; nt < 4; ++nt)
      bf[nt] = *(const half8*)&Bs[(wn + nt * 16 + l15) * 32 + l4 * 8];
#pragma unroll
    for (int mt = 0; mt < 4; ++mt)
#pragma unroll
      for (int nt = 0; nt < 4; ++nt)
        acc[mt][nt] = __builtin_amdgcn_mfma_f32_16x16x32_f16(
            af[mt], bf[nt], acc[mt][nt], 0, 0, 0);
  }

#pragma unroll
  for (int mt = 0; mt < 4; ++mt)
#pragma unroll
    for (int r = 0; r < 4; ++r) {
      const int row = bm + wm + mt * 16 + l4 * 4 + r;
#pragma unroll
      for (int nt = 0; nt < 4; ++nt) {
        const int col = bn + wn + nt * 16 + l15;
        const float val = acc[mt][nt][r] + bias[col];
        if (mode == 1) {
          const int i = row >> 2, b = row & 3, h = col >> 6, d = col & 63;
          qf[(((size_t)(b * 16 + h) * 1024 + i) << 6) + d] = (_Float16)val;
        } else if (mode == 2) {
          const int j = row >> 2, b = row & 3;
          const int c = col & 1023, h = c >> 6, d = c & 63;
          if ((col >> 10) == 0)
            kf[(((size_t)(b * 16 + h) * 2048 + j) << 6) + d] = (_Float16)val;
          else
            vfT[(((size_t)(b * 16 + h) * 64 + d) << 11) + j] = (_Float16)val;
        } else {
          const int h = col >> 6, d = col & 63;
          rf[(((size_t)h * 2048 + row) << 6) + d] = (_Float16)val;
        }
      }
    }
}

// ---------------------------------------------------------------------------
// proj GEMM: out f32 [M][N] = A @ Bt^T + bias
// ---------------------------------------------------------------------------
__global__ __launch_bounds__(256, 2) void gemm_proj(
    const _Float16* __restrict__ A, const _Float16* __restrict__ Bt,
    const float* __restrict__ bias, float* __restrict__ out0, int M, int N,
    int K) {
  __shared__ _Float16 As[128 * 32];
  __shared__ _Float16 Bs[128 * 32];
  const int t = threadIdx.x, w = t >> 6, l = t & 63;
  const int l15 = l & 15, l4 = l >> 4;
  const int bm = blockIdx.y * 128, bn = blockIdx.x * 128;
  const int wm = (w >> 1) * 64, wn = (w & 1) * 64;

  f32x4 acc[4][4];
  const f32x4 z4 = {0.f, 0.f, 0.f, 0.f};
#pragma unroll
  for (int i = 0; i < 4; ++i)
#pragma unroll
    for (int j = 0; j < 4; ++j) acc[i][j] = z4;

  const char* Abase = (const char*)A + (size_t)bm * K * 2;
  const char* Bbase = (const char*)Bt + (size_t)bn * K * 2;
  char* Asl = (char*)As;
  char* Bsl = (char*)Bs;

  for (int k0 = 0; k0 < K; k0 += 32) {
    __syncthreads();
#pragma unroll
    for (int iss = 0; iss < 2; ++iss) {
      const int off = w * 1024 + iss * 4096 + l * 16;
      const int row = off >> 6, kb = off & 63;
      load_lds16(Abase + (size_t)row * (K * 2) + k0 * 2 + kb,
                 Asl + w * 1024 + iss * 4096);
      load_lds16(Bbase + (size_t)row * (K * 2) + k0 * 2 + kb,
                 Bsl + w * 1024 + iss * 4096);
    }
    __syncthreads();
    half8 af[4], bf[4];
#pragma unroll
    for (int mt = 0; mt < 4; ++mt)
      af[mt] = *(const half8*)&As[(wm + mt * 16 + l15) * 32 + l4 * 8];
#pragma unroll
    for (int nt = 0; nt < 4; ++nt)
      bf[nt] = *(const half8*)&Bs[(wn + nt * 16 + l15) * 32 + l4 * 8];
#pragma unroll
    for (int mt = 0; mt < 4; ++mt)
#pragma unroll
      for (int nt = 0; nt < 4; ++nt)
        acc[mt][nt] = __builtin_amdgcn_mfma_f32_16x16x32_f16(
            af[mt], bf[nt], acc[mt][nt], 0, 0, 0);
  }

#pragma unroll
  for (int mt = 0; mt < 4; ++mt)
#pragma unroll
    for (int r = 0; r < 4; ++r) {
      const int row = bm + wm + mt * 16 + l4 * 4 + r;
#pragma unroll
      for (int nt = 0; nt < 4; ++nt) {
        const int col = bn + wn + nt * 16 + l15;
        out0[(size_t)row * N + col] = acc[mt][nt][r] + bias[col];
      }
    }
}

// ---------------------------------------------------------------------------
// fused uk[bh][j] = u_h . k  and  vr[h][m] = v_h . r
// ---------------------------------------------------------------------------
__global__ __launch_bounds__(256) void ukvr_dot(
    const _Float16* __restrict__ kf, const _Float16* __restrict__ rf,
    const float* __restrict__ u, const float* __restrict__ v,
    float* __restrict__ uk, float* __restrict__ vr) {
  const int t = threadIdx.x, by = blockIdx.y;
  const int g = t >> 4, l15 = t & 15;
  const int row = blockIdx.x * 16 + g;
  const _Float16* mat;
  const float* uv;
  float* out;
  int h;
  if (by < 64) {
    h = by & 15;
    mat = kf + (((size_t)by * 2048 + row) << 6);
    uv = u; out = uk + (size_t)by * 2048 + row;
  } else {
    h = by - 64;
    mat = rf + (((size_t)h * 2048 + row) << 6);
    uv = v; out = vr + (size_t)h * 2048 + row;
  }
  float s = 0.f;
#pragma unroll
  for (int i = 0; i < 4; ++i)
    s += (float)mat[l15 * 4 + i] * uv[h * 64 + l15 * 4 + i];
#pragma unroll
  for (int off = 1; off < 16; off <<= 1) s += __shfl_xor(s, off, 64);
  if (l15 == 0) *out = s;
}

// ---------------------------------------------------------------------------
// MFMA flash attention v3.
//  - 40 KB LDS exactly -> 4 blocks/CU; uk/vr read per-lane from global (L2).
//  - pA XOR-swizzled (stride 64, col ^ (row&7)*8).
//  - LPT: logical q-tile = 15 - blockIdx.x (long blocks first).
// ---------------------------------------------------------------------------
__global__ __launch_bounds__(256, 4) void attn_mfma(
    const _Float16* __restrict__ qf,   // [bh][1024][64]
    const _Float16* __restrict__ kf,   // [bh][2048][64]
    const _Float16* __restrict__ vfT,  // [bh][64][2048]
    const _Float16* __restrict__ rf,   // [h][2048][64]
    const float* __restrict__ ukw,     // [bh][2048]
    const float* __restrict__ vrw,     // [h][2048]
    _Float16* __restrict__ attn_out)   // [i*4+b][1024] f16
{
  __shared__ _Float16 ks[64 * 64];     // [j][d] swizzled
  __shared__ _Float16 vts[64 * 64];    // [d][j] swizzled
  __shared__ _Float16 rs[128 * 64];    // ring of r rows, swizzled
  __shared__ _Float16 pA[4][16 * 64];  // per-wave probs, A-layout, XOR-swizzled

  const int t = threadIdx.x, w = t >> 6, l = t & 63;
  const int l15 = l & 15, l4 = l >> 4;
  const int bx = 15 - (int)blockIdx.x;  // LPT: longest first
  const int i0 = bx * 64;
  const int bh = blockIdx.y, h = bh & 15, b = bh >> 4;

  const char* kfb = (const char*)(kf + (((size_t)bh * 2048) << 6));
  const char* vg = (const char*)(vfT + (((size_t)bh) << 17));
  const char* rg = (const char*)(rf + (((size_t)h) << 17));
  const float* ukb = ukw + (size_t)bh * 2048;
  const float* vrb = vrw + (size_t)h * 2048;

  // q A-fragments in registers for the whole loop
  half8 qa0, qa1;
  {
    const _Float16* qrow =
        qf + (((size_t)bh * 1024 + i0 + w * 16 + l15) << 6) + l4 * 8;
    qa0 = *(const half8*)qrow;
    qa1 = *(const half8*)(qrow + 32);
  }
  const f32x4 z4 = {0.f, 0.f, 0.f, 0.f};
  f32x4 o[4];
  o[0] = z4; o[1] = z4; o[2] = z4; o[3] = z4;
  float lsum[4] = {0.f, 0.f, 0.f, 0.f};

  // ---- prologue: stage full 128-row r window (slot = m & 127) ----
  const int mb0 = 960 - i0;  // m_base at jt=0 (>= 0)
  {
    const int base0 = mb0 & 127;
#pragma unroll
    for (int iss = 0; iss < 4; ++iss) {
      const int off = w * 1024 + iss * 4096 + l * 16;
      const int slot = off >> 7;
      const int cph = (off >> 4) & 7;
      int m = mb0 + ((slot - base0) & 127);
      m = m < 2047 ? m : 2047;
      load_lds16(rg + (size_t)m * 128 + ((cph ^ (slot & 7)) << 4),
                 (char*)rs + off);
    }
  }

  const int njt = bx + 17;
  for (int jt = 0; jt < njt; ++jt) {
    const int j0 = jt * 64;
    const int m_base = j0 - i0 + 960;
    __syncthreads();  // prior tile's reads done before overwrite
    // ---- stage K, V^T (swizzled source) ----
    {
      const char* kg = kfb + (size_t)j0 * 128;
#pragma unroll
      for (int iss = 0; iss < 2; ++iss) {
        const int off = w * 1024 + iss * 4096 + l * 16;
        const int row = off >> 7;
        const int cph = (off >> 4) & 7;
        const int sw = ((cph ^ (row & 7)) << 4);
        load_lds16(kg + (size_t)row * 128 + sw, (char*)ks + off);
        load_lds16(vg + (size_t)row * 4096 + (size_t)j0 * 2 + sw,
                   (char*)vts + off);
      }
    }
    // ---- stage 64 new r rows into the ring ----
    if (jt > 0) {
      const int sb = (m_base + 64) & 127;  // 0 or 64 (contiguous slots)
#pragma unroll
      for (int iss = 0; iss < 2; ++iss) {
        const int off = w * 1024 + iss * 4096 + l * 16;
        const int q = off >> 7;
        const int cph = (off >> 4) & 7;
        const int slot = sb + q;
        int m = m_base + 64 + q;
        m = m < 2047 ? m : 2047;
        load_lds16(rg + (size_t)m * 128 + ((cph ^ (slot & 7)) << 4),
                   (char*)rs + slot * 128 + cph * 16);
      }
    }
    // ---- per-lane uk / vr values straight from global (L2-resident) ----
    float uk4[4], vr_reg[5];
#pragma unroll
    for (int nt = 0; nt < 4; ++nt) uk4[nt] = ukb[j0 + nt * 16 + l15];
#pragma unroll
    for (int p = 0; p < 5; ++p) {
      int m = m_base + (3 - w + p) * 16 + l15;
      m = m < 2047 ? m : 2047;
      vr_reg[p] = vrb[m];
    }
    __syncthreads();

    // ---- content scores S = Q.K^T (16x64 per wave) ----
    f32x4 sc[4];
#pragma unroll
    for (int nt = 0; nt < 4; ++nt) {
      const int row = nt * 16 + l15;
      const int rsw = row & 7;
      const half8 b0 = *(const half8*)&ks[row * 64 + ((l4 ^ rsw) * 8)];
      const half8 b1 = *(const half8*)&ks[row * 64 + (((4 + l4) ^ rsw) * 8)];
      f32x4 cc = z4;
      cc = __builtin_amdgcn_mfma_f32_16x16x32_f16(qa0, b0, cc, 0, 0, 0);
      cc = __builtin_amdgcn_mfma_f32_16x16x32_f16(qa1, b1, cc, 0, 0, 0);
      sc[nt] = cc;
    }
    // ---- position scores: 5 tiles covering this wave's 79-wide window ----
    f32x4 accP[5];
#pragma unroll
    for (int p = 0; p < 5; ++p) {
      const int m = m_base + (3 - w + p) * 16 + l15;
      const int slot = m & 127;
      const int ssw = slot & 7;
      const half8 b0 = *(const half8*)&rs[slot * 64 + ((l4 ^ ssw) * 8)];
      const half8 b1 = *(const half8*)&rs[slot * 64 + (((4 + l4) ^ ssw) * 8)];
      f32x4 cc = z4;
      cc = __builtin_amdgcn_mfma_f32_16x16x32_f16(qa0, b0, cc, 0, 0, 0);
      cc = __builtin_amdgcn_mfma_f32_16x16x32_f16(qa1, b1, cc, 0, 0, 0);
      accP[p] = cc;
    }

    // ---- softmax (no max subtraction; logits bounded) + P in A-layout ----
    const int cw = i0 - j0 + 1024 + 16 * w;  // mask: jl > cw + (4*l4+r)
#pragma unroll
    for (int r = 0; r < 4; ++r) {
      const int thr = 4 * l4 + r;
      const int srcl = (l4 << 4) | ((15 + l15 - thr) & 15);
      float rot[5];
#pragma unroll
      for (int p = 0; p < 5; ++p)
        rot[p] = __shfl(accP[p][r] + vr_reg[p], srcl, 64);
      float esum = 0.f;
      const int sw = (thr & 7) * 8;
#pragma unroll
      for (int nt = 0; nt < 4; ++nt) {
        const float pv = (l15 <= thr) ? rot[nt] : rot[nt + 1];
        const float s = (sc[nt][r] + uk4[nt] + pv) * 0.125f;
        const bool masked = (16 * nt + l15) > (cw + thr);
        const float e = masked ? 0.f : __expf(s);
        esum += e;
        pA[w][thr * 64 + ((16 * nt + l15) ^ sw)] = (_Float16)e;
      }
      lsum[r] += esum;
    }
    // ---- PV: O += P.V ----
#pragma unroll
    for (int kk = 0; kk < 2; ++kk) {
      const half8 a8 =
          *(const half8*)&pA[w][l15 * 64 + ((kk * 32 + l4 * 8) ^ ((l15 & 7) * 8))];
#pragma unroll
      for (int nt = 0; nt < 4; ++nt) {
        const int row = nt * 16 + l15;
        const half8 b8 =
            *(const half8*)&vts[row * 64 + ((((kk << 2) + l4) ^ (row & 7)) * 8)];
        o[nt] = __builtin_amdgcn_mfma_f32_16x16x32_f16(a8, b8, o[nt], 0, 0, 0);
      }
    }
  }

  // ---- epilogue: row-sum across the 16-lane group, normalize, store ----
#pragma unroll
  for (int r = 0; r < 4; ++r) {
    float s = lsum[r];
    s += __shfl_xor(s, 1, 64);
    s += __shfl_xor(s, 2, 64);
    s += __shfl_xor(s, 4, 64);
    s += __shfl_xor(s, 8, 64);
    const float inv = 1.0f / s;
    const int i = i0 + w * 16 + l4 * 4 + r;
    const size_t base = ((size_t)i * 4 + b) * 1024 + h * 64;
#pragma unroll
    for (int nt = 0; nt < 4; ++nt)
      attn_out[base + nt * 16 + l15] = (_Float16)(o[nt][r] * inv);
  }
}

// ---------------------------------------------------------------------------
extern "C" void kernel_launch(void* const* d_in, const int* in_sizes, int n_in,
                              void* d_out, int out_size, void* d_ws,
                              size_t ws_size, hipStream_t stream) {
  const float* inputs   = (const float*)d_in[0];
  const float* pos_emb  = (const float*)d_in[1];
  const float* full_inp = (const float*)d_in[2];
  const float* u        = (const float*)d_in[3];
  const float* v        = (const float*)d_in[4];
  const float* W_kv   = (const float*)d_in[6];
  const float* b_kv   = (const float*)d_in[7];
  const float* W_q    = (const float*)d_in[8];
  const float* b_q    = (const float*)d_in[9];
  const float* W_pos  = (const float*)d_in[10];
  const float* b_pos  = (const float*)d_in[11];
  const float* W_proj = (const float*)d_in[12];
  const float* b_proj = (const float*)d_in[13];
  float* out = (float*)d_out;

  char* ws = (char*)d_ws;
  const size_t MB = 1024 * 1024;
  _Float16* in_q_h    = (_Float16*)(ws);            // 8 MB  (4096x1024)
  _Float16* in_full_h = (_Float16*)(ws + 8 * MB);   // 16 MB (8192x1024)
  _Float16* in_pos_h  = (_Float16*)(ws + 24 * MB);  // 4 MB  (2048x1024)
  _Float16* attn_h    = (_Float16*)(ws + 28 * MB);  // 8 MB  (4096x1024)
  _Float16* wq_t      = (_Float16*)(ws + 36 * MB);  // 2 MB  (1024x1024)
  _Float16* wkv_t     = (_Float16*)(ws + 38 * MB);  // 4 MB  (2048x1024)
  _Float16* wpos_t    = (_Float16*)(ws + 42 * MB);  // 2 MB
  _Float16* wproj_t   = (_Float16*)(ws + 44 * MB);  // 2 MB
  _Float16* qf        = (_Float16*)(ws + 46 * MB);  // 8 MB  [bh][1024][64]
  _Float16* kf        = (_Float16*)(ws + 54 * MB);  // 16 MB [bh][2048][64]
  _Float16* vfT       = (_Float16*)(ws + 70 * MB);  // 16 MB [bh][64][2048]
  _Float16* rf        = (_Float16*)(ws + 86 * MB);  // 4 MB  [h][2048][64]
  float* uk_ws        = (float*)(ws + 90 * MB);     // 512 KB [bh][2048]
  float* vr_ws        = (float*)(ws + 91 * MB);     // 128 KB [h][2048]

  const dim3 blk(256);
  prep<<<dim3(15616), blk, 0, stream>>>(inputs, full_inp, pos_emb, W_q, W_kv,
                                        W_pos, W_proj, in_q_h, in_full_h,
                                        in_pos_h, wq_t, wkv_t, wpos_t, wproj_t);
  gemm3<<<dim3(1408), blk, 0, stream>>>(in_q_h, in_full_h, in_pos_h, wq_t,
                                        wkv_t, wpos_t, b_q, b_kv, b_pos, qf,
                                        kf, vfT, rf);
  ukvr_dot<<<dim3(128, 80), blk, 0, stream>>>(kf, rf, u, v, uk_ws, vr_ws);
  attn_mfma<<<dim3(16, 64), blk, 0, stream>>>(qf, kf, vfT, rf, uk_ws, vr_ws,
                                              attn_h);
  gemm_proj<<<dim3(8, 32), blk, 0, stream>>>(attn_h, wproj_t, b_proj, out,
                                             4096, 1024, 1024);
}

// Round 5
// 409.092 us; speedup vs baseline: 11.2421x; 1.0269x over previous
//
#include <hip/hip_runtime.h>

// AttentionXL: CUR=1024, FULL=2048, BS=4, D=1024, HN=16, HD=64, PREV=1024
// f16 MFMA 16x16x32 everywhere; fp32 accumulate/softmax.

typedef _Float16 half8 __attribute__((ext_vector_type(8)));
typedef _Float16 half4v __attribute__((ext_vector_type(4)));
typedef float f32x4 __attribute__((ext_vector_type(4)));

typedef const __attribute__((address_space(1))) void* gas_ptr;
typedef __attribute__((address_space(3))) void* las_ptr;

__device__ __forceinline__ void load_lds16(const void* g, void* l) {
  __builtin_amdgcn_global_load_lds((gas_ptr)g, (las_ptr)l, 16, 0, 0);
}

// ---------------------------------------------------------------------------
// fused prep: fp32->f16 converts (blocks [0,14336)) + weight transpose
// (blocks [14336,15616)).
// ---------------------------------------------------------------------------
__global__ __launch_bounds__(256) void prep(
    const float* __restrict__ inputs, const float* __restrict__ full_inp,
    const float* __restrict__ pos_emb, const float* __restrict__ Wq,
    const float* __restrict__ Wkv, const float* __restrict__ Wpos,
    const float* __restrict__ Wproj, _Float16* __restrict__ o_in,
    _Float16* __restrict__ o_full, _Float16* __restrict__ o_pos,
    _Float16* __restrict__ owq, _Float16* __restrict__ owkv,
    _Float16* __restrict__ owpos, _Float16* __restrict__ owproj) {
  __shared__ _Float16 tile[64][65];
  const int bx = blockIdx.x;
  const int t = threadIdx.x;
  if (bx < 14336) {
    size_t g = (size_t)bx * 256 + t;  // float4-group id
    const float* src;
    _Float16* dst;
    size_t idx;
    if (g < (1u << 20)) {
      src = inputs; dst = o_in; idx = g;
    } else if (g < (3u << 20)) {
      src = full_inp; dst = o_full; idx = g - (1u << 20);
    } else {
      src = pos_emb; dst = o_pos; idx = g - (3u << 20);
    }
    float4 v = *(const float4*)(src + idx * 4);
    half4v h;
    h[0] = (_Float16)v.x; h[1] = (_Float16)v.y;
    h[2] = (_Float16)v.z; h[3] = (_Float16)v.w;
    *(half4v*)(dst + idx * 4) = h;
    return;
  }
  const int wb = bx - 14336;
  const float* W;
  _Float16* Wt;
  int N, tidx;
  if (wb < 256) { W = Wq; Wt = owq; N = 1024; tidx = wb; }
  else if (wb < 768) { W = Wkv; Wt = owkv; N = 2048; tidx = wb - 256; }
  else if (wb < 1024) { W = Wpos; Wt = owpos; N = 1024; tidx = wb - 768; }
  else { W = Wproj; Wt = owproj; N = 1024; tidx = wb - 1024; }
  const int K = 1024;
  const int n0 = (tidx % (N >> 6)) * 64, k0 = (tidx / (N >> 6)) * 64;
  const int rr = t >> 2, cc = (t & 3) * 16;
#pragma unroll
  for (int i = 0; i < 4; ++i) {
    float4 v = *(const float4*)&W[(size_t)(k0 + rr) * N + n0 + cc + i * 4];
    tile[rr][cc + i * 4 + 0] = (_Float16)v.x;
    tile[rr][cc + i * 4 + 1] = (_Float16)v.y;
    tile[rr][cc + i * 4 + 2] = (_Float16)v.z;
    tile[rr][cc + i * 4 + 3] = (_Float16)v.w;
  }
  __syncthreads();
  const int n = t >> 2, kc = (t & 3) * 16;
#pragma unroll
  for (int i = 0; i < 4; ++i) {
    half4v h;
    h[0] = tile[kc + i * 4 + 0][n];
    h[1] = tile[kc + i * 4 + 1][n];
    h[2] = tile[kc + i * 4 + 2][n];
    h[3] = tile[kc + i * 4 + 3][n];
    *(half4v*)&Wt[(size_t)(n0 + n) * K + k0 + kc + i * 4] = h;
  }
}

// ---------------------------------------------------------------------------
// Fused q/kv/r GEMM: one dispatch, 1408 blocks.
//   [0,256):    q  -> qfu[bh][i][d] = q+b+u  AND  qfv[bh][i][d] = q+b+v
//   [256,1280): kv -> kf[bh][j][d] + vfT[bh][d][j]
//   [1280,1408): r -> rf[h][m][d]
// ---------------------------------------------------------------------------
__global__ __launch_bounds__(256, 2) void gemm3(
    const _Float16* __restrict__ Aq, const _Float16* __restrict__ Akv,
    const _Float16* __restrict__ Ar, const _Float16* __restrict__ Btq,
    const _Float16* __restrict__ Btkv, const _Float16* __restrict__ Btr,
    const float* __restrict__ bq, const float* __restrict__ bkv,
    const float* __restrict__ br, const float* __restrict__ uu,
    const float* __restrict__ vv, _Float16* __restrict__ qfu,
    _Float16* __restrict__ qfv, _Float16* __restrict__ kf,
    _Float16* __restrict__ vfT, _Float16* __restrict__ rf) {
  __shared__ _Float16 As[128 * 32];
  __shared__ _Float16 Bs[128 * 32];
  const int gb = blockIdx.x;
  const _Float16* A;
  const _Float16* Bt;
  const float* bias;
  int mode, bm, bn;
  if (gb < 256) {
    mode = 1; A = Aq; Bt = Btq; bias = bq;
    bn = (gb & 7) * 128; bm = (gb >> 3) * 128;
  } else if (gb < 1280) {
    mode = 2; A = Akv; Bt = Btkv; bias = bkv;
    const int j = gb - 256;
    bn = (j & 15) * 128; bm = (j >> 4) * 128;
  } else {
    mode = 3; A = Ar; Bt = Btr; bias = br;
    const int j = gb - 1280;
    bn = (j & 7) * 128; bm = (j >> 3) * 128;
  }
  const int K = 1024;
  const int t = threadIdx.x, w = t >> 6, l = t & 63;
  const int l15 = l & 15, l4 = l >> 4;
  const int wm = (w >> 1) * 64, wn = (w & 1) * 64;

  f32x4 acc[4][4];
  const f32x4 z4 = {0.f, 0.f, 0.f, 0.f};
#pragma unroll
  for (int i = 0; i < 4; ++i)
#pragma unroll
    for (int j = 0; j < 4; ++j) acc[i][j] = z4;

  const char* Abase = (const char*)A + (size_t)bm * K * 2;
  const char* Bbase = (const char*)Bt + (size_t)bn * K * 2;
  char* Asl = (char*)As;
  char* Bsl = (char*)Bs;

  for (int k0 = 0; k0 < K; k0 += 32) {
    __syncthreads();
#pragma unroll
    for (int iss = 0; iss < 2; ++iss) {
      const int off = w * 1024 + iss * 4096 + l * 16;
      const int row = off >> 6, kb = off & 63;
      load_lds16(Abase + (size_t)row * (K * 2) + k0 * 2 + kb,
                 Asl + w * 1024 + iss * 4096);
      load_lds16(Bbase + (size_t)row * (K * 2) + k0 * 2 + kb,
                 Bsl + w * 1024 + iss * 4096);
    }
    __syncthreads();
    half8 af[4], bf[4];
#pragma unroll
    for (int mt = 0; mt < 4; ++mt)
      af[mt] = *(const half8*)&As[(wm + mt * 16 + l15) * 32 + l4 * 8];
#pragma unroll
    for (int nt = 0; nt < 4; ++nt)
      bf[nt] = *(const half8*)&Bs[(wn + nt * 16 + l15) * 32 + l4 * 8];
#pragma unroll
    for (int mt = 0; mt < 4; ++mt)
#pragma unroll
      for (int nt = 0; nt < 4; ++nt)
        acc[mt][nt] = __builtin_amdgcn_mfma_f32_16x16x32_f16(
            af[mt], bf[nt], acc[mt][nt], 0, 0, 0);
  }

#pragma unroll
  for (int mt = 0; mt < 4; ++mt)
#pragma unroll
    for (int r = 0; r < 4; ++r) {
      const int row = bm + wm + mt * 16 + l4 * 4 + r;
#pragma unroll
      for (int nt = 0; nt < 4; ++nt) {
        const int col = bn + wn + nt * 16 + l15;
        const float val = acc[mt][nt][r] + bias[col];
        if (mode == 1) {
          const int i = row >> 2, b = row & 3, h = col >> 6, d = col & 63;
          const size_t idx = (((size_t)(b * 16 + h) * 1024 + i) << 6) + d;
          qfu[idx] = (_Float16)(val + uu[col]);
          qfv[idx] = (_Float16)(val + vv[col]);
        } else if (mode == 2) {
          const int j = row >> 2, b = row & 3;
          const int c = col & 1023, h = c >> 6, d = c & 63;
          if ((col >> 10) == 0)
            kf[(((size_t)(b * 16 + h) * 2048 + j) << 6) + d] = (_Float16)val;
          else
            vfT[(((size_t)(b * 16 + h) * 64 + d) << 11) + j] = (_Float16)val;
        } else {
          const int h = col >> 6, d = col & 63;
          rf[(((size_t)h * 2048 + row) << 6) + d] = (_Float16)val;
        }
      }
    }
}

// ---------------------------------------------------------------------------
// proj GEMM: out f32 [M][N] = A @ Bt^T + bias
// ---------------------------------------------------------------------------
__global__ __launch_bounds__(256, 2) void gemm_proj(
    const _Float16* __restrict__ A, const _Float16* __restrict__ Bt,
    const float* __restrict__ bias, float* __restrict__ out0, int M, int N,
    int K) {
  __shared__ _Float16 As[128 * 32];
  __shared__ _Float16 Bs[128 * 32];
  const int t = threadIdx.x, w = t >> 6, l = t & 63;
  const int l15 = l & 15, l4 = l >> 4;
  const int bm = blockIdx.y * 128, bn = blockIdx.x * 128;
  const int wm = (w >> 1) * 64, wn = (w & 1) * 64;

  f32x4 acc[4][4];
  const f32x4 z4 = {0.f, 0.f, 0.f, 0.f};
#pragma unroll
  for (int i = 0; i < 4; ++i)
#pragma unroll
    for (int j = 0; j < 4; ++j) acc[i][j] = z4;

  const char* Abase = (const char*)A + (size_t)bm * K * 2;
  const char* Bbase = (const char*)Bt + (size_t)bn * K * 2;
  char* Asl = (char*)As;
  char* Bsl = (char*)Bs;

  for (int k0 = 0; k0 < K; k0 += 32) {
    __syncthreads();
#pragma unroll
    for (int iss = 0; iss < 2; ++iss) {
      const int off = w * 1024 + iss * 4096 + l * 16;
      const int row = off >> 6, kb = off & 63;
      load_lds16(Abase + (size_t)row * (K * 2) + k0 * 2 + kb,
                 Asl + w * 1024 + iss * 4096);
      load_lds16(Bbase + (size_t)row * (K * 2) + k0 * 2 + kb,
                 Bsl + w * 1024 + iss * 4096);
    }
    __syncthreads();
    half8 af[4], bf[4];
#pragma unroll
    for (int mt = 0; mt < 4; ++mt)
      af[mt] = *(const half8*)&As[(wm + mt * 16 + l15) * 32 + l4 * 8];
#pragma unroll
    for (int nt = 0; nt < 4; ++nt)
      bf[nt] = *(const half8*)&Bs[(wn + nt * 16 + l15) * 32 + l4 * 8];
#pragma unroll
    for (int mt = 0; mt < 4; ++mt)
#pragma unroll
      for (int nt = 0; nt < 4; ++nt)
        acc[mt][nt] = __builtin_amdgcn_mfma_f32_16x16x32_f16(
            af[mt], bf[nt], acc[mt][nt], 0, 0, 0);
  }

#pragma unroll
  for (int mt = 0; mt < 4; ++mt)
#pragma unroll
    for (int r = 0; r < 4; ++r) {
      const int row = bm + wm + mt * 16 + l4 * 4 + r;
#pragma unroll
      for (int nt = 0; nt < 4; ++nt) {
        const int col = bn + wn + nt * 16 + l15;
        out0[(size_t)row * N + col] = acc[mt][nt][r] + bias[col];
      }
    }
}

// ---------------------------------------------------------------------------
// MFMA flash attention v4: cross-iteration prefetch.
//  - ks/vts double-buffered; rs = 192-row ring with 64-row prefetch.
//  - prefetch for jt+1 issued right after the barrier of jt; the compiler's
//    vmcnt(0) drain at the NEXT barrier lands after a full compute phase.
//  - u folded into qfu (content), v folded into qfv (position): no uk/vr.
//  - LDS exactly 64 KB -> 2 blocks/CU; no VGPR squeeze (no spill).
// ---------------------------------------------------------------------------
__global__ __launch_bounds__(256, 2) void attn_mfma(
    const _Float16* __restrict__ qfu,  // [bh][1024][64]  (q + u)
    const _Float16* __restrict__ qfv,  // [bh][1024][64]  (q + v)
    const _Float16* __restrict__ kf,   // [bh][2048][64]
    const _Float16* __restrict__ vfT,  // [bh][64][2048]
    const _Float16* __restrict__ rf,   // [h][2048][64]
    _Float16* __restrict__ attn_out)   // [i*4+b][1024] f16
{
  __shared__ _Float16 ks[2 * 64 * 64];   // [buf][j][d] swizzled
  __shared__ _Float16 vts[2 * 64 * 64];  // [buf][d][j] swizzled
  __shared__ _Float16 rs[192 * 64];      // ring (slot = m % 192), swizzled
  __shared__ _Float16 pA[4][16 * 64];    // per-wave probs, A-layout, swizzled

  const int t = threadIdx.x, w = t >> 6, l = t & 63;
  const int l15 = l & 15, l4 = l >> 4;
  const int bx = 15 - (int)blockIdx.x;  // LPT: longest first
  const int i0 = bx * 64;
  const int bh = blockIdx.y, h = bh & 15, b = bh >> 4;

  const char* kfb = (const char*)(kf + (((size_t)bh * 2048) << 6));
  const char* vg = (const char*)(vfT + (((size_t)bh) << 17));
  const char* rg = (const char*)(rf + (((size_t)h) << 17));

  // q fragments (content and position variants) in registers for the loop
  half8 qa0, qa1, qv0, qv1;
  {
    const size_t qo = (((size_t)bh * 1024 + i0 + w * 16 + l15) << 6) + l4 * 8;
    qa0 = *(const half8*)(qfu + qo);
    qa1 = *(const half8*)(qfu + qo + 32);
    qv0 = *(const half8*)(qfv + qo);
    qv1 = *(const half8*)(qfv + qo + 32);
  }
  const f32x4 z4 = {0.f, 0.f, 0.f, 0.f};
  f32x4 o[4];
  o[0] = z4; o[1] = z4; o[2] = z4; o[3] = z4;
  float lsum[4] = {0.f, 0.f, 0.f, 0.f};

  const int mb0 = 960 - i0;  // m_base at jt=0 (>=0, multiple of 64)
  const int njt = bx + 17;

  // ---- prologue: stage tile 0 (buf 0) + initial 128-row r window ----
  {
#pragma unroll
    for (int iss = 0; iss < 2; ++iss) {
      const int off = w * 1024 + iss * 4096 + l * 16;
      const int row = off >> 7;
      const int cph = (off >> 4) & 7;
      const int sw = ((cph ^ (row & 7)) << 4);
      load_lds16(kfb + (size_t)row * 128 + sw, (char*)ks + off);
      load_lds16(vg + (size_t)row * 4096 + sw, (char*)vts + off);
    }
#pragma unroll
    for (int iss = 0; iss < 4; ++iss) {
      const int off = w * 1024 + iss * 4096 + l * 16;
      const int q = off >> 7;  // 0..127
      const int cph = (off >> 4) & 7;
      const int slot = (mb0 + q) % 192;
      int m = mb0 + q;
      m = m < 2047 ? m : 2047;
      load_lds16(rg + (size_t)m * 128 + ((cph ^ (slot & 7)) << 4),
                 (char*)rs + slot * 128 + cph * 16);
    }
  }

  for (int jt = 0; jt < njt; ++jt) {
    const int j0 = jt * 64;
    const int m_base = j0 - i0 + 960;
    __syncthreads();  // drains prefetch issued at jt-1; releases jt-1 buffers

    // ---- prefetch tile jt+1 (other buffer) + 64 new r rows ----
    if (jt + 1 < njt) {
      const int bufo = ((jt + 1) & 1) * 8192;  // bytes
      const char* kg = kfb + (size_t)(j0 + 64) * 128;
#pragma unroll
      for (int iss = 0; iss < 2; ++iss) {
        const int off = w * 1024 + iss * 4096 + l * 16;
        const int row = off >> 7;
        const int cph = (off >> 4) & 7;
        const int sw = ((cph ^ (row & 7)) << 4);
        load_lds16(kg + (size_t)row * 128 + sw, (char*)ks + bufo + off);
        load_lds16(vg + (size_t)row * 4096 + (size_t)(j0 + 64) * 2 + sw,
                   (char*)vts + bufo + off);
      }
      const int m0 = m_base + 128;
#pragma unroll
      for (int iss = 0; iss < 2; ++iss) {
        const int off = w * 1024 + iss * 4096 + l * 16;
        const int q = off >> 7;  // 0..63
        const int cph = (off >> 4) & 7;
        const int slot = (m0 + q) % 192;
        int m = m0 + q;
        m = m < 2047 ? m : 2047;
        load_lds16(rg + (size_t)m * 128 + ((cph ^ (slot & 7)) << 4),
                   (char*)rs + slot * 128 + cph * 16);
      }
    }

    const _Float16* ksc = ks + (jt & 1) * 4096;
    const _Float16* vtc = vts + (jt & 1) * 4096;

    // ---- content scores S = (Q+u).K^T (16x64 per wave) ----
    f32x4 sc[4];
#pragma unroll
    for (int nt = 0; nt < 4; ++nt) {
      const int row = nt * 16 + l15;
      const int rsw = row & 7;
      const half8 b0 = *(const half8*)&ksc[row * 64 + ((l4 ^ rsw) * 8)];
      const half8 b1 = *(const half8*)&ksc[row * 64 + (((4 + l4) ^ rsw) * 8)];
      f32x4 cc = z4;
      cc = __builtin_amdgcn_mfma_f32_16x16x32_f16(qa0, b0, cc, 0, 0, 0);
      cc = __builtin_amdgcn_mfma_f32_16x16x32_f16(qa1, b1, cc, 0, 0, 0);
      sc[nt] = cc;
    }
    // ---- position scores (Q+v).R^T: 5 tiles over this wave's 79-window ----
    f32x4 accP[5];
#pragma unroll
    for (int p = 0; p < 5; ++p) {
      const int m = m_base + (3 - w + p) * 16 + l15;
      const int slot = m % 192;
      const int ssw = slot & 7;
      const half8 b0 = *(const half8*)&rs[slot * 64 + ((l4 ^ ssw) * 8)];
      const half8 b1 = *(const half8*)&rs[slot * 64 + (((4 + l4) ^ ssw) * 8)];
      f32x4 cc = z4;
      cc = __builtin_amdgcn_mfma_f32_16x16x32_f16(qv0, b0, cc, 0, 0, 0);
      cc = __builtin_amdgcn_mfma_f32_16x16x32_f16(qv1, b1, cc, 0, 0, 0);
      accP[p] = cc;
    }

    // ---- softmax (no max subtraction; logits bounded) + P in A-layout ----
    const int cw = i0 - j0 + 1024 + 16 * w;  // mask: jl > cw + (4*l4+r)
#pragma unroll
    for (int r = 0; r < 4; ++r) {
      const int thr = 4 * l4 + r;
      const int srcl = (l4 << 4) | ((15 + l15 - thr) & 15);
      float rot[5];
#pragma unroll
      for (int p = 0; p < 5; ++p) rot[p] = __shfl(accP[p][r], srcl, 64);
      float esum = 0.f;
      const int sw2 = (thr & 7) * 8;
#pragma unroll
      for (int nt = 0; nt < 4; ++nt) {
        const float pv = (l15 <= thr) ? rot[nt] : rot[nt + 1];
        const float s = (sc[nt][r] + pv) * 0.125f;
        const bool masked = (16 * nt + l15) > (cw + thr);
        const float e = masked ? 0.f : __expf(s);
        esum += e;
        pA[w][thr * 64 + ((16 * nt + l15) ^ sw2)] = (_Float16)e;
      }
      lsum[r] += esum;
    }
    // ---- PV: O += P.V ----
#pragma unroll
    for (int kk = 0; kk < 2; ++kk) {
      const half8 a8 = *(const half8*)&pA[w][l15 * 64 +
                                            ((kk * 32 + l4 * 8) ^ ((l15 & 7) * 8))];
#pragma unroll
      for (int nt = 0; nt < 4; ++nt) {
        const int row = nt * 16 + l15;
        const half8 b8 =
            *(const half8*)&vtc[row * 64 + ((((kk << 2) + l4) ^ (row & 7)) * 8)];
        o[nt] = __builtin_amdgcn_mfma_f32_16x16x32_f16(a8, b8, o[nt], 0, 0, 0);
      }
    }
  }

  // ---- epilogue: row-sum across the 16-lane group, normalize, store ----
#pragma unroll
  for (int r = 0; r < 4; ++r) {
    float s = lsum[r];
    s += __shfl_xor(s, 1, 64);
    s += __shfl_xor(s, 2, 64);
    s += __shfl_xor(s, 4, 64);
    s += __shfl_xor(s, 8, 64);
    const float inv = 1.0f / s;
    const int i = i0 + w * 16 + l4 * 4 + r;
    const size_t base = ((size_t)i * 4 + b) * 1024 + h * 64;
#pragma unroll
    for (int nt = 0; nt < 4; ++nt)
      attn_out[base + nt * 16 + l15] = (_Float16)(o[nt][r] * inv);
  }
}

// ---------------------------------------------------------------------------
extern "C" void kernel_launch(void* const* d_in, const int* in_sizes, int n_in,
                              void* d_out, int out_size, void* d_ws,
                              size_t ws_size, hipStream_t stream) {
  const float* inputs   = (const float*)d_in[0];
  const float* pos_emb  = (const float*)d_in[1];
  const float* full_inp = (const float*)d_in[2];
  const float* u        = (const float*)d_in[3];
  const float* v        = (const float*)d_in[4];
  const float* W_kv   = (const float*)d_in[6];
  const float* b_kv   = (const float*)d_in[7];
  const float* W_q    = (const float*)d_in[8];
  const float* b_q    = (const float*)d_in[9];
  const float* W_pos  = (const float*)d_in[10];
  const float* b_pos  = (const float*)d_in[11];
  const float* W_proj = (const float*)d_in[12];
  const float* b_proj = (const float*)d_in[13];
  float* out = (float*)d_out;

  char* ws = (char*)d_ws;
  const size_t MB = 1024 * 1024;
  _Float16* in_q_h    = (_Float16*)(ws);            // 8 MB  (4096x1024)
  _Float16* in_full_h = (_Float16*)(ws + 8 * MB);   // 16 MB (8192x1024)
  _Float16* in_pos_h  = (_Float16*)(ws + 24 * MB);  // 4 MB  (2048x1024)
  _Float16* attn_h    = (_Float16*)(ws + 28 * MB);  // 8 MB  (4096x1024)
  _Float16* wq_t      = (_Float16*)(ws + 36 * MB);  // 2 MB  (1024x1024)
  _Float16* wkv_t     = (_Float16*)(ws + 38 * MB);  // 4 MB  (2048x1024)
  _Float16* wpos_t    = (_Float16*)(ws + 42 * MB);  // 2 MB
  _Float16* wproj_t   = (_Float16*)(ws + 44 * MB);  // 2 MB
  _Float16* qfu       = (_Float16*)(ws + 46 * MB);  // 8 MB  [bh][1024][64]
  _Float16* kf        = (_Float16*)(ws + 54 * MB);  // 16 MB [bh][2048][64]
  _Float16* vfT       = (_Float16*)(ws + 70 * MB);  // 16 MB [bh][64][2048]
  _Float16* rf        = (_Float16*)(ws + 86 * MB);  // 4 MB  [h][2048][64]
  _Float16* qfv       = (_Float16*)(ws + 90 * MB);  // 8 MB  [bh][1024][64]

  const dim3 blk(256);
  prep<<<dim3(15616), blk, 0, stream>>>(inputs, full_inp, pos_emb, W_q, W_kv,
                                        W_pos, W_proj, in_q_h, in_full_h,
                                        in_pos_h, wq_t, wkv_t, wpos_t, wproj_t);
  gemm3<<<dim3(1408), blk, 0, stream>>>(in_q_h, in_full_h, in_pos_h, wq_t,
                                        wkv_t, wpos_t, b_q, b_kv, b_pos, u, v,
                                        qfu, qfv, kf, vfT, rf);
  attn_mfma<<<dim3(16, 64), blk, 0, stream>>>(qfu, qfv, kf, vfT, rf, attn_h);
  gemm_proj<<<dim3(8, 32), blk, 0, stream>>>(attn_h, wproj_t, b_proj, out,
                                             4096, 1024, 1024);
}

// Round 6
// 337.747 us; speedup vs baseline: 13.6168x; 1.2112x over previous
//
#include <hip/hip_runtime.h>

// AttentionXL: CUR=1024, FULL=2048, BS=4, D=1024, HN=16, HD=64, PREV=1024
// f16 MFMA 16x16x32 everywhere; fp32 accumulate/softmax.
// Scores pre-scaled: qfu = (q+b+u)*0.125; qv = qfu + (v-u)*0.125 in-register.

typedef _Float16 half8 __attribute__((ext_vector_type(8)));
typedef _Float16 half4v __attribute__((ext_vector_type(4)));
typedef float f32x4 __attribute__((ext_vector_type(4)));

typedef const __attribute__((address_space(1))) void* gas_ptr;
typedef __attribute__((address_space(3))) void* las_ptr;

__device__ __forceinline__ void load_lds16(const void* g, void* l) {
  __builtin_amdgcn_global_load_lds((gas_ptr)g, (las_ptr)l, 16, 0, 0);
}

// ---------------------------------------------------------------------------
// prep: activation fp32->f16 with b-major row permute (blocks [0,14336)) +
// weight convert+transpose (blocks [14336,15616)).
//  in_q_h  [b*1024 + i][:] <- inputs[i*4+b][:]
//  in_full_h[b*2048 + j][:] <- full_inp[j*4+b][:]
//  in_pos_h plain copy.
// ---------------------------------------------------------------------------
__global__ __launch_bounds__(256) void prep(
    const float* __restrict__ inputs, const float* __restrict__ full_inp,
    const float* __restrict__ pos_emb, const float* __restrict__ Wq,
    const float* __restrict__ Wkv, const float* __restrict__ Wpos,
    const float* __restrict__ Wproj, _Float16* __restrict__ o_in,
    _Float16* __restrict__ o_full, _Float16* __restrict__ o_pos,
    _Float16* __restrict__ owq, _Float16* __restrict__ owkv,
    _Float16* __restrict__ owpos, _Float16* __restrict__ owproj) {
  __shared__ _Float16 tile[64][65];
  const int bx = blockIdx.x;
  const int t = threadIdx.x;
  if (bx < 14336) {
    size_t g = (size_t)bx * 256 + t;  // dst float4-group id
    const float* src;
    _Float16* dst;
    size_t sg;
    if (g < (1u << 20)) {  // inputs -> in_q_h, b-major
      const int rd = (int)(g >> 8), b = rd >> 10, i = rd & 1023;
      src = inputs; dst = o_in;
      sg = ((size_t)(i * 4 + b) << 8) + (g & 255);
    } else if (g < (3u << 20)) {  // full_inp -> in_full_h, b-major
      const size_t gd = g - (1u << 20);
      const int rd = (int)(gd >> 8), b = rd >> 11, j = rd & 2047;
      src = full_inp; dst = o_full;
      sg = ((size_t)(j * 4 + b) << 8) + (gd & 255);
      g = gd + (1u << 20);  // keep dst index
      dst = o_full;
      // dst group index within o_full:
      sg = sg;  // src group
      // store at gd
      float4 vv = *(const float4*)(src + sg * 4);
      half4v hh;
      hh[0] = (_Float16)vv.x; hh[1] = (_Float16)vv.y;
      hh[2] = (_Float16)vv.z; hh[3] = (_Float16)vv.w;
      *(half4v*)(dst + gd * 4) = hh;
      return;
    } else {  // pos_emb plain
      const size_t gd = g - (3u << 20);
      float4 vv = *(const float4*)(pos_emb + gd * 4);
      half4v hh;
      hh[0] = (_Float16)vv.x; hh[1] = (_Float16)vv.y;
      hh[2] = (_Float16)vv.z; hh[3] = (_Float16)vv.w;
      *(half4v*)(o_pos + gd * 4) = hh;
      return;
    }
    // in_q_h path
    float4 vv = *(const float4*)(src + sg * 4);
    half4v hh;
    hh[0] = (_Float16)vv.x; hh[1] = (_Float16)vv.y;
    hh[2] = (_Float16)vv.z; hh[3] = (_Float16)vv.w;
    *(half4v*)(dst + (g & ((1u << 20) - 1)) * 4) = hh;
    return;
  }
  const int wb = bx - 14336;
  const float* W;
  _Float16* Wt;
  int N, tidx;
  if (wb < 256) { W = Wq; Wt = owq; N = 1024; tidx = wb; }
  else if (wb < 768) { W = Wkv; Wt = owkv; N = 2048; tidx = wb - 256; }
  else if (wb < 1024) { W = Wpos; Wt = owpos; N = 1024; tidx = wb - 768; }
  else { W = Wproj; Wt = owproj; N = 1024; tidx = wb - 1024; }
  const int K = 1024;
  const int n0 = (tidx % (N >> 6)) * 64, k0 = (tidx / (N >> 6)) * 64;
  const int rr = t >> 2, cc = (t & 3) * 16;
#pragma unroll
  for (int i = 0; i < 4; ++i) {
    float4 v = *(const float4*)&W[(size_t)(k0 + rr) * N + n0 + cc + i * 4];
    tile[rr][cc + i * 4 + 0] = (_Float16)v.x;
    tile[rr][cc + i * 4 + 1] = (_Float16)v.y;
    tile[rr][cc + i * 4 + 2] = (_Float16)v.z;
    tile[rr][cc + i * 4 + 3] = (_Float16)v.w;
  }
  __syncthreads();
  const int n = t >> 2, kc = (t & 3) * 16;
#pragma unroll
  for (int i = 0; i < 4; ++i) {
    half4v h;
    h[0] = tile[kc + i * 4 + 0][n];
    h[1] = tile[kc + i * 4 + 1][n];
    h[2] = tile[kc + i * 4 + 2][n];
    h[3] = tile[kc + i * 4 + 3][n];
    *(half4v*)&Wt[(size_t)(n0 + n) * K + k0 + kc + i * 4] = h;
  }
}

// ---------------------------------------------------------------------------
// Fused q/kv/r GEMM (A matrices are b-major). 1408 blocks.
//   [0,256):    q  -> qfu[bh][i][d] = (q+b+u)*0.125
//   [256,1280): kv -> kf[bh][j][d]; V-half via LDS transpose -> vfT[bh][d][j]
//   [1280,1408): r -> rf[h][m][d]
// ---------------------------------------------------------------------------
__global__ __launch_bounds__(256, 2) void gemm3(
    const _Float16* __restrict__ Aq, const _Float16* __restrict__ Akv,
    const _Float16* __restrict__ Ar, const _Float16* __restrict__ Btq,
    const _Float16* __restrict__ Btkv, const _Float16* __restrict__ Btr,
    const float* __restrict__ bq, const float* __restrict__ bkv,
    const float* __restrict__ br, const float* __restrict__ uu,
    _Float16* __restrict__ qfu, _Float16* __restrict__ kf,
    _Float16* __restrict__ vfT, _Float16* __restrict__ rf) {
  __shared__ _Float16 smem[128 * 66];  // K-loop: As=smem[0..4K), Bs=[4K..8K); epilogue: 128x66 tile
  _Float16* As = smem;
  _Float16* Bs = smem + 4096;
  const int gb = blockIdx.x;
  const _Float16* A;
  const _Float16* Bt;
  const float* bias;
  int mode, bm, bn;
  if (gb < 256) {
    mode = 1; A = Aq; Bt = Btq; bias = bq;
    bn = (gb & 7) * 128; bm = (gb >> 3) * 128;
  } else if (gb < 1280) {
    mode = 2; A = Akv; Bt = Btkv; bias = bkv;
    const int j = gb - 256;
    bn = (j & 15) * 128; bm = (j >> 4) * 128;
  } else {
    mode = 3; A = Ar; Bt = Btr; bias = br;
    const int j = gb - 1280;
    bn = (j & 7) * 128; bm = (j >> 3) * 128;
  }
  const int K = 1024;
  const int t = threadIdx.x, w = t >> 6, l = t & 63;
  const int l15 = l & 15, l4 = l >> 4;
  const int wm = (w >> 1) * 64, wn = (w & 1) * 64;

  f32x4 acc[4][4];
  const f32x4 z4 = {0.f, 0.f, 0.f, 0.f};
#pragma unroll
  for (int i = 0; i < 4; ++i)
#pragma unroll
    for (int j = 0; j < 4; ++j) acc[i][j] = z4;

  const char* Abase = (const char*)A + (size_t)bm * K * 2;
  const char* Bbase = (const char*)Bt + (size_t)bn * K * 2;

  for (int k0 = 0; k0 < K; k0 += 32) {
    __syncthreads();
#pragma unroll
    for (int iss = 0; iss < 2; ++iss) {
      const int off = w * 1024 + iss * 4096 + l * 16;
      const int row = off >> 6, kb = off & 63;
      load_lds16(Abase + (size_t)row * (K * 2) + k0 * 2 + kb,
                 (char*)As + off);
      load_lds16(Bbase + (size_t)row * (K * 2) + k0 * 2 + kb,
                 (char*)Bs + off);
    }
    __syncthreads();
    half8 af[4], bf[4];
#pragma unroll
    for (int mt = 0; mt < 4; ++mt)
      af[mt] = *(const half8*)&As[(wm + mt * 16 + l15) * 32 + l4 * 8];
#pragma unroll
    for (int nt = 0; nt < 4; ++nt)
      bf[nt] = *(const half8*)&Bs[(wn + nt * 16 + l15) * 32 + l4 * 8];
#pragma unroll
    for (int mt = 0; mt < 4; ++mt)
#pragma unroll
      for (int nt = 0; nt < 4; ++nt)
        acc[mt][nt] = __builtin_amdgcn_mfma_f32_16x16x32_f16(
            af[mt], bf[nt], acc[mt][nt], 0, 0, 0);
  }

  if (mode == 2 && bn >= 1024) {
    // ---- V half: LDS transpose -> coalesced vfT[bh][d][j] stores ----
    const int b = bm >> 11, j0m = bm & 2047;
    const int hbase = (bn - 1024) >> 6;  // even
#pragma unroll
    for (int ch = 0; ch < 2; ++ch) {
      __syncthreads();
      if (((wn >> 6) & 1) == ch) {
#pragma unroll
        for (int mt = 0; mt < 4; ++mt)
#pragma unroll
          for (int r = 0; r < 4; ++r) {
            const int rowl = wm + mt * 16 + l4 * 4 + r;
#pragma unroll
            for (int nt = 0; nt < 4; ++nt) {
              const int coll = nt * 16 + l15;
              smem[rowl * 66 + coll] =
                  (_Float16)(acc[mt][nt][r] + bias[bn + wn + coll]);
            }
          }
      }
      __syncthreads();
#pragma unroll
      for (int it = 0; it < 4; ++it) {
        const int c = t + 256 * it;
        const int d = c >> 4, ck = c & 15;
        half8 v8;
#pragma unroll
        for (int z = 0; z < 8; ++z) v8[z] = smem[(ck * 8 + z) * 66 + d];
        *(half8*)&vfT[(((size_t)(b * 16 + hbase + ch) * 64 + d) << 11) + j0m +
                      ck * 8] = v8;
      }
    }
    return;
  }

#pragma unroll
  for (int mt = 0; mt < 4; ++mt)
#pragma unroll
    for (int r = 0; r < 4; ++r) {
      const int rowl = wm + mt * 16 + l4 * 4 + r;
#pragma unroll
      for (int nt = 0; nt < 4; ++nt) {
        const int col = bn + wn + nt * 16 + l15;
        const float val = acc[mt][nt][r] + bias[col];
        if (mode == 1) {
          const int b = bm >> 10, i0m = bm & 1023;
          const int h = col >> 6, d = col & 63;
          qfu[(((size_t)(b * 16 + h) * 1024 + i0m + rowl) << 6) + d] =
              (_Float16)((val + uu[col]) * 0.125f);
        } else if (mode == 2) {
          const int b = bm >> 11, j0m = bm & 2047;
          const int h = col >> 6, d = col & 63;
          kf[(((size_t)(b * 16 + h) * 2048 + j0m + rowl) << 6) + d] =
              (_Float16)val;
        } else {
          const int h = col >> 6, d = col & 63;
          rf[(((size_t)h * 2048 + bm + rowl) << 6) + d] = (_Float16)val;
        }
      }
    }
}

// ---------------------------------------------------------------------------
// proj GEMM: out f32 [M][N] = A @ Bt^T + bias
// ---------------------------------------------------------------------------
__global__ __launch_bounds__(256, 2) void gemm_proj(
    const _Float16* __restrict__ A, const _Float16* __restrict__ Bt,
    const float* __restrict__ bias, float* __restrict__ out0, int M, int N,
    int K) {
  __shared__ _Float16 As[128 * 32];
  __shared__ _Float16 Bs[128 * 32];
  const int t = threadIdx.x, w = t >> 6, l = t & 63;
  const int l15 = l & 15, l4 = l >> 4;
  const int bm = blockIdx.y * 128, bn = blockIdx.x * 128;
  const int wm = (w >> 1) * 64, wn = (w & 1) * 64;

  f32x4 acc[4][4];
  const f32x4 z4 = {0.f, 0.f, 0.f, 0.f};
#pragma unroll
  for (int i = 0; i < 4; ++i)
#pragma unroll
    for (int j = 0; j < 4; ++j) acc[i][j] = z4;

  const char* Abase = (const char*)A + (size_t)bm * K * 2;
  const char* Bbase = (const char*)Bt + (size_t)bn * K * 2;

  for (int k0 = 0; k0 < K; k0 += 32) {
    __syncthreads();
#pragma unroll
    for (int iss = 0; iss < 2; ++iss) {
      const int off = w * 1024 + iss * 4096 + l * 16;
      const int row = off >> 6, kb = off & 63;
      load_lds16(Abase + (size_t)row * (K * 2) + k0 * 2 + kb,
                 (char*)As + off);
      load_lds16(Bbase + (size_t)row * (K * 2) + k0 * 2 + kb,
                 (char*)Bs + off);
    }
    __syncthreads();
    half8 af[4], bf[4];
#pragma unroll
    for (int mt = 0; mt < 4; ++mt)
      af[mt] = *(const half8*)&As[(wm + mt * 16 + l15) * 32 + l4 * 8];
#pragma unroll
    for (int nt = 0; nt < 4; ++nt)
      bf[nt] = *(const half8*)&Bs[(wn + nt * 16 + l15) * 32 + l4 * 8];
#pragma unroll
    for (int mt = 0; mt < 4; ++mt)
#pragma unroll
      for (int nt = 0; nt < 4; ++nt)
        acc[mt][nt] = __builtin_amdgcn_mfma_f32_16x16x32_f16(
            af[mt], bf[nt], acc[mt][nt], 0, 0, 0);
  }

#pragma unroll
  for (int mt = 0; mt < 4; ++mt)
#pragma unroll
    for (int r = 0; r < 4; ++r) {
      const int row = bm + wm + mt * 16 + l4 * 4 + r;
#pragma unroll
      for (int nt = 0; nt < 4; ++nt) {
        const int col = bn + wn + nt * 16 + l15;
        out0[(size_t)row * N + col] = acc[mt][nt][r] + bias[col];
      }
    }
}

// ---------------------------------------------------------------------------
// MFMA flash attention v5.
//  - single-buffered ks/vts; rs = 256-slot ring (slot = m & 255, no modulo).
//  - qv fragments built in-register from (v-u)*0.125 (no qfv array).
//  - mask fast-path: mask logic only when wave-uniform cw < 63.
//  - XCD swizzle: same-bh blocks share dispatch residue mod 8.
//  - LDS 56 KB -> 2 blocks/CU.
// ---------------------------------------------------------------------------
__global__ __launch_bounds__(256, 2) void attn_mfma(
    const _Float16* __restrict__ qfu,  // [bh][1024][64]  (q+b+u)*0.125
    const _Float16* __restrict__ kf,   // [bh][2048][64]
    const _Float16* __restrict__ vfT,  // [bh][64][2048]
    const _Float16* __restrict__ rf,   // [h][2048][64]
    const float* __restrict__ u,       // [16][64]
    const float* __restrict__ v,       // [16][64]
    _Float16* __restrict__ attn_out)   // [i*4+b][1024] f16
{
  __shared__ _Float16 ks[64 * 64];     // [j][d] swizzled
  __shared__ _Float16 vts[64 * 64];    // [d][j] swizzled
  __shared__ _Float16 rs[256 * 64];    // ring (slot = m & 255), swizzled
  __shared__ _Float16 pA[4][16 * 64];  // per-wave probs, A-layout, swizzled

  const int t = threadIdx.x, w = t >> 6, l = t & 63;
  const int l15 = l & 15, l4 = l >> 4;
  const int id = blockIdx.x;
  // XCD swizzle: bh = ((id>>3)&7)*8 + (id&7); qtile = id>>6 (LPT: reversed)
  const int bh = ((id >> 3) & 7) * 8 + (id & 7);
  const int bx = 15 - (id >> 6);
  const int i0 = bx * 64;
  const int h = bh & 15, b = bh >> 4;

  const char* kfb = (const char*)(kf + (((size_t)bh * 2048) << 6));
  const char* vg = (const char*)(vfT + (((size_t)bh) << 17));
  const char* rg = (const char*)(rf + (((size_t)h) << 17));

  // q fragments; qv = qa + (v-u)*0.125 in-register
  half8 qa0, qa1, qv0, qv1;
  {
    const size_t qo = (((size_t)bh * 1024 + i0 + w * 16 + l15) << 6) + l4 * 8;
    qa0 = *(const half8*)(qfu + qo);
    qa1 = *(const half8*)(qfu + qo + 32);
    half8 dl0, dl1;
#pragma unroll
    for (int z = 0; z < 8; ++z) {
      const int di = l4 * 8 + z;
      dl0[z] = (_Float16)(0.125f * (v[h * 64 + di] - u[h * 64 + di]));
      dl1[z] = (_Float16)(0.125f * (v[h * 64 + 32 + di] - u[h * 64 + 32 + di]));
    }
    qv0 = qa0 + dl0;
    qv1 = qa1 + dl1;
  }
  const f32x4 z4 = {0.f, 0.f, 0.f, 0.f};
  f32x4 o[4];
  o[0] = z4; o[1] = z4; o[2] = z4; o[3] = z4;
  float lsum[4] = {0.f, 0.f, 0.f, 0.f};

  const int mb0 = 960 - i0;  // m_base at jt=0 (>=0, multiple of 64)
  const int njt = bx + 17;

  // ---- prologue: stage initial 128-row r window into ring ----
#pragma unroll
  for (int iss = 0; iss < 4; ++iss) {
    const int off = w * 1024 + iss * 4096 + l * 16;
    const int q = off >> 7;  // 0..127
    const int cph = (off >> 4) & 7;
    const int slot = (mb0 + q) & 255;
    int m = mb0 + q;
    m = m < 2047 ? m : 2047;
    load_lds16(rg + (size_t)m * 128 + ((cph ^ (slot & 7)) << 4),
               (char*)rs + slot * 128 + cph * 16);
  }

  for (int jt = 0; jt < njt; ++jt) {
    const int j0 = jt * 64;
    const int m_base = j0 - i0 + 960;
    __syncthreads();  // prior tile's reads done before overwrite
    // ---- stage K, V^T (swizzled source) ----
    {
      const char* kg = kfb + (size_t)j0 * 128;
#pragma unroll
      for (int iss = 0; iss < 2; ++iss) {
        const int off = w * 1024 + iss * 4096 + l * 16;
        const int row = off >> 7;
        const int cph = (off >> 4) & 7;
        const int sw = ((cph ^ (row & 7)) << 4);
        load_lds16(kg + (size_t)row * 128 + sw, (char*)ks + off);
        load_lds16(vg + (size_t)row * 4096 + (size_t)j0 * 2 + sw,
                   (char*)vts + off);
      }
    }
    // ---- stage 64 new r rows [m_base+64, m_base+128) into ring ----
    if (jt > 0) {
      const int m0 = m_base + 64;
#pragma unroll
      for (int iss = 0; iss < 2; ++iss) {
        const int off = w * 1024 + iss * 4096 + l * 16;
        const int q = off >> 7;  // 0..63
        const int cph = (off >> 4) & 7;
        const int slot = (m0 + q) & 255;
        int m = m0 + q;
        m = m < 2047 ? m : 2047;
        load_lds16(rg + (size_t)m * 128 + ((cph ^ (slot & 7)) << 4),
                   (char*)rs + slot * 128 + cph * 16);
      }
    }
    __syncthreads();

    // ---- content scores (16x64 per wave) ----
    f32x4 sc[4];
#pragma unroll
    for (int nt = 0; nt < 4; ++nt) {
      const int row = nt * 16 + l15;
      const int rsw = row & 7;
      const half8 b0 = *(const half8*)&ks[row * 64 + ((l4 ^ rsw) * 8)];
      const half8 b1 = *(const half8*)&ks[row * 64 + (((4 + l4) ^ rsw) * 8)];
      f32x4 cc = z4;
      cc = __builtin_amdgcn_mfma_f32_16x16x32_f16(qa0, b0, cc, 0, 0, 0);
      cc = __builtin_amdgcn_mfma_f32_16x16x32_f16(qa1, b1, cc, 0, 0, 0);
      sc[nt] = cc;
    }
    // ---- position scores: 5 tiles over this wave's 79-wide window ----
    f32x4 accP[5];
#pragma unroll
    for (int p = 0; p < 5; ++p) {
      const int m = m_base + (3 - w + p) * 16 + l15;
      const int slot = m & 255;
      const int ssw = slot & 7;
      const half8 b0 = *(const half8*)&rs[slot * 64 + ((l4 ^ ssw) * 8)];
      const half8 b1 = *(const half8*)&rs[slot * 64 + (((4 + l4) ^ ssw) * 8)];
      f32x4 cc = z4;
      cc = __builtin_amdgcn_mfma_f32_16x16x32_f16(qv0, b0, cc, 0, 0, 0);
      cc = __builtin_amdgcn_mfma_f32_16x16x32_f16(qv1, b1, cc, 0, 0, 0);
      accP[p] = cc;
    }

    // ---- softmax + P into A-layout (scores pre-scaled by 0.125) ----
    const int cw = i0 - j0 + 1024 + 16 * w;  // mask: jl > cw + (4*l4+r)
    if (cw >= 63) {  // wave-uniform: no masking possible in this tile
#pragma unroll
      for (int r = 0; r < 4; ++r) {
        const int thr = 4 * l4 + r;
        const int srcl = (l4 << 4) | ((15 + l15 - thr) & 15);
        float rot[5];
#pragma unroll
        for (int p = 0; p < 5; ++p) rot[p] = __shfl(accP[p][r], srcl, 64);
        float esum = 0.f;
        const int sw2 = (thr & 7) * 8;
#pragma unroll
        for (int nt = 0; nt < 4; ++nt) {
          const float pv = (l15 <= thr) ? rot[nt] : rot[nt + 1];
          const float e = __expf(sc[nt][r] + pv);
          esum += e;
          pA[w][thr * 64 + ((16 * nt + l15) ^ sw2)] = (_Float16)e;
        }
        lsum[r] += esum;
      }
    } else {
#pragma unroll
      for (int r = 0; r < 4; ++r) {
        const int thr = 4 * l4 + r;
        const int srcl = (l4 << 4) | ((15 + l15 - thr) & 15);
        float rot[5];
#pragma unroll
        for (int p = 0; p < 5; ++p) rot[p] = __shfl(accP[p][r], srcl, 64);
        float esum = 0.f;
        const int sw2 = (thr & 7) * 8;
#pragma unroll
        for (int nt = 0; nt < 4; ++nt) {
          const float pv = (l15 <= thr) ? rot[nt] : rot[nt + 1];
          const bool masked = (16 * nt + l15) > (cw + thr);
          const float e = masked ? 0.f : __expf(sc[nt][r] + pv);
          esum += e;
          pA[w][thr * 64 + ((16 * nt + l15) ^ sw2)] = (_Float16)e;
        }
        lsum[r] += esum;
      }
    }
    // ---- PV: O += P.V ----
#pragma unroll
    for (int kk = 0; kk < 2; ++kk) {
      const half8 a8 = *(const half8*)&pA[w][l15 * 64 + ((kk * 32 + l4 * 8) ^
                                                        ((l15 & 7) * 8))];
#pragma unroll
      for (int nt = 0; nt < 4; ++nt) {
        const int row = nt * 16 + l15;
        const half8 b8 =
            *(const half8*)&vts[row * 64 + ((((kk << 2) + l4) ^ (row & 7)) * 8)];
        o[nt] = __builtin_amdgcn_mfma_f32_16x16x32_f16(a8, b8, o[nt], 0, 0, 0);
      }
    }
  }

  // ---- epilogue ----
#pragma unroll
  for (int r = 0; r < 4; ++r) {
    float s = lsum[r];
    s += __shfl_xor(s, 1, 64);
    s += __shfl_xor(s, 2, 64);
    s += __shfl_xor(s, 4, 64);
    s += __shfl_xor(s, 8, 64);
    const float inv = 1.0f / s;
    const int i = i0 + w * 16 + l4 * 4 + r;
    const size_t base = ((size_t)i * 4 + b) * 1024 + h * 64;
#pragma unroll
    for (int nt = 0; nt < 4; ++nt)
      attn_out[base + nt * 16 + l15] = (_Float16)(o[nt][r] * inv);
  }
}

// ---------------------------------------------------------------------------
extern "C" void kernel_launch(void* const* d_in, const int* in_sizes, int n_in,
                              void* d_out, int out_size, void* d_ws,
                              size_t ws_size, hipStream_t stream) {
  const float* inputs   = (const float*)d_in[0];
  const float* pos_emb  = (const float*)d_in[1];
  const float* full_inp = (const float*)d_in[2];
  const float* u        = (const float*)d_in[3];
  const float* v        = (const float*)d_in[4];
  const float* W_kv   = (const float*)d_in[6];
  const float* b_kv   = (const float*)d_in[7];
  const float* W_q    = (const float*)d_in[8];
  const float* b_q    = (const float*)d_in[9];
  const float* W_pos  = (const float*)d_in[10];
  const float* b_pos  = (const float*)d_in[11];
  const float* W_proj = (const float*)d_in[12];
  const float* b_proj = (const float*)d_in[13];
  float* out = (float*)d_out;

  char* ws = (char*)d_ws;
  const size_t MB = 1024 * 1024;
  _Float16* in_q_h    = (_Float16*)(ws);            // 8 MB  (b-major 4096x1024)
  _Float16* in_full_h = (_Float16*)(ws + 8 * MB);   // 16 MB (b-major 8192x1024)
  _Float16* in_pos_h  = (_Float16*)(ws + 24 * MB);  // 4 MB  (2048x1024)
  _Float16* attn_h    = (_Float16*)(ws + 28 * MB);  // 8 MB  (4096x1024)
  _Float16* wq_t      = (_Float16*)(ws + 36 * MB);  // 2 MB
  _Float16* wkv_t     = (_Float16*)(ws + 38 * MB);  // 4 MB
  _Float16* wpos_t    = (_Float16*)(ws + 42 * MB);  // 2 MB
  _Float16* wproj_t   = (_Float16*)(ws + 44 * MB);  // 2 MB
  _Float16* qfu       = (_Float16*)(ws + 46 * MB);  // 8 MB  [bh][1024][64]
  _Float16* kf        = (_Float16*)(ws + 54 * MB);  // 16 MB [bh][2048][64]
  _Float16* vfT       = (_Float16*)(ws + 70 * MB);  // 16 MB [bh][64][2048]
  _Float16* rf        = (_Float16*)(ws + 86 * MB);  // 4 MB  [h][2048][64]

  const dim3 blk(256);
  prep<<<dim3(15616), blk, 0, stream>>>(inputs, full_inp, pos_emb, W_q, W_kv,
                                        W_pos, W_proj, in_q_h, in_full_h,
                                        in_pos_h, wq_t, wkv_t, wpos_t, wproj_t);
  gemm3<<<dim3(1408), blk, 0, stream>>>(in_q_h, in_full_h, in_pos_h, wq_t,
                                        wkv_t, wpos_t, b_q, b_kv, b_pos, u,
                                        qfu, kf, vfT, rf);
  attn_mfma<<<dim3(1024), blk, 0, stream>>>(qfu, kf, vfT, rf, u, v, attn_h);
  gemm_proj<<<dim3(8, 32), blk, 0, stream>>>(attn_h, wproj_t, b_proj, out,
                                             4096, 1024, 1024);
}